// Round 2
// baseline (1012.724 us; speedup 1.0000x reference)
//
#include <hip/hip_runtime.h>
#include <hip/hip_bf16.h>

// GQA forward, fp32 baseline (round 1): identical math to round 0 but the
// output buffer is fp32 (deduced from out_npz_mb=15.5 => 16MB raw fp32).
// B=2, S=2048, HIDDEN=1024, 16 heads x 64 dim, RoPE over full hidden (half=512).
// d_ws usage: q,k,v,attn_out fp32 scratch = 64 MB.

constexpr int Bb  = 2;
constexpr int Ss  = 2048;
constexpr int Hh  = 1024;
constexpr int NHh = 16;
constexpr int Mm  = Bb * Ss;   // 4096 rows

// ---------------- QKV projection: C[m,n] = x[m,:] . W[n,:] + b[n] ----------------
// One kernel covers q|k|v by column block. 128x128 tile, 256 thr, 8x8 micro-tile.
__global__ __launch_bounds__(256) void qkv_gemm_k(
    const float* __restrict__ x,
    const float* __restrict__ Wq, const float* __restrict__ bq,
    const float* __restrict__ Wk, const float* __restrict__ bk,
    const float* __restrict__ Wv, const float* __restrict__ bv,
    float* __restrict__ q, float* __restrict__ k, float* __restrict__ v)
{
    __shared__ float As[16][128];
    __shared__ float Bs[16][128];
    const int bm = blockIdx.x * 128;
    const int gn = blockIdx.y * 128;

    const float* W; const float* bias; float* outp; int n0;
    if (gn < 1024)      { W = Wq; bias = bq; outp = q; n0 = gn; }
    else if (gn < 2048) { W = Wk; bias = bk; outp = k; n0 = gn - 1024; }
    else                { W = Wv; bias = bv; outp = v; n0 = gn - 2048; }

    const int tid = threadIdx.x;
    const int tx = tid & 15;
    const int ty = tid >> 4;

    float acc[8][8];
    #pragma unroll
    for (int i = 0; i < 8; ++i)
        #pragma unroll
        for (int j = 0; j < 8; ++j) acc[i][j] = 0.f;

    for (int k0 = 0; k0 < 1024; k0 += 16) {
        __syncthreads();
        #pragma unroll
        for (int f = 0; f < 2; ++f) {
            int idx = tid + f * 256;        // 0..511
            int r   = idx >> 2;             // 0..127
            int kq  = (idx & 3) << 2;       // 0,4,8,12
            float4 av = *(const float4*)&x[(size_t)(bm + r) * 1024 + k0 + kq];
            As[kq + 0][r] = av.x; As[kq + 1][r] = av.y;
            As[kq + 2][r] = av.z; As[kq + 3][r] = av.w;
            float4 wv = *(const float4*)&W[(size_t)(n0 + r) * 1024 + k0 + kq];
            Bs[kq + 0][r] = wv.x; Bs[kq + 1][r] = wv.y;
            Bs[kq + 2][r] = wv.z; Bs[kq + 3][r] = wv.w;
        }
        __syncthreads();
        #pragma unroll
        for (int kk = 0; kk < 16; ++kk) {
            float a[8], b[8];
            *(float4*)&a[0] = *(const float4*)&As[kk][ty * 8];
            *(float4*)&a[4] = *(const float4*)&As[kk][ty * 8 + 4];
            *(float4*)&b[0] = *(const float4*)&Bs[kk][tx * 8];
            *(float4*)&b[4] = *(const float4*)&Bs[kk][tx * 8 + 4];
            #pragma unroll
            for (int i = 0; i < 8; ++i)
                #pragma unroll
                for (int j = 0; j < 8; ++j)
                    acc[i][j] = fmaf(a[i], b[j], acc[i][j]);
        }
    }
    #pragma unroll
    for (int i = 0; i < 8; ++i) {
        const int row = bm + ty * 8 + i;
        float4 o0, o1;
        o0.x = acc[i][0] + bias[n0 + tx * 8 + 0];
        o0.y = acc[i][1] + bias[n0 + tx * 8 + 1];
        o0.z = acc[i][2] + bias[n0 + tx * 8 + 2];
        o0.w = acc[i][3] + bias[n0 + tx * 8 + 3];
        o1.x = acc[i][4] + bias[n0 + tx * 8 + 4];
        o1.y = acc[i][5] + bias[n0 + tx * 8 + 5];
        o1.z = acc[i][6] + bias[n0 + tx * 8 + 6];
        o1.w = acc[i][7] + bias[n0 + tx * 8 + 7];
        *(float4*)&outp[(size_t)row * 1024 + n0 + tx * 8]     = o0;
        *(float4*)&outp[(size_t)row * 1024 + n0 + tx * 8 + 4] = o1;
    }
}

// ---------------- RoPE over full hidden: pair (j, j+512), in place on q and k ----
__global__ __launch_bounds__(256) void rope_k(float* __restrict__ q, float* __restrict__ kk)
{
    int idx = blockIdx.x * 256 + threadIdx.x;   // Mm*512 total, exact grid
    int row = idx >> 9;
    int j   = idx & 511;
    int pos = row & (Ss - 1);
    float inv = powf(10000.0f, -(float)j * (1.0f / 512.0f));
    float ang = (float)pos * inv;
    float sn, cs;
    sincosf(ang, &sn, &cs);
    size_t base = (size_t)row * 1024;
    float a = q[base + j], b = q[base + j + 512];
    q[base + j]       = a * cs - b * sn;
    q[base + j + 512] = b * cs + a * sn;
    float c = kk[base + j], d = kk[base + j + 512];
    kk[base + j]       = c * cs - d * sn;
    kk[base + j + 512] = d * cs + c * sn;
}

// ---------------- Flash attention (fp32): 64-query block per WG -------------------
// Thread layout 16x16: ty -> 4 queries, tx -> 4 keys (score) / 4 dims (PV).
// P is written back into the K-tile LDS buffer after scores (saves 17 KB).
__global__ __launch_bounds__(256) void flash_k(
    const float* __restrict__ q, const float* __restrict__ k,
    const float* __restrict__ v, const int* __restrict__ mask,
    float* __restrict__ ao)
{
    __shared__ float Qs[64][64];    // [d][qi], scaled by 1/8; written once
    __shared__ float Ks[64][68];    // [d][kj] during scores; reused as P[kj][qi]
    __shared__ float Vs[64][64];    // [kj][d]
    __shared__ int   Ms[64];

    const int qb  = blockIdx.x;
    const int h   = blockIdx.y;
    const int bz  = blockIdx.z;
    const int tid = threadIdx.x;
    const int tx  = tid & 15, ty = tid >> 4;
    const int tx4 = tx * 4,  ty4 = ty * 4;

    #pragma unroll
    for (int f = 0; f < 4; ++f) {
        int idx = tid + f * 256;
        int qi  = idx >> 4;
        int dq  = (idx & 15) << 2;
        float4 t = *(const float4*)&q[((size_t)(bz * Ss + qb * 64 + qi)) * 1024 + h * 64 + dq];
        Qs[dq + 0][qi] = t.x * 0.125f;
        Qs[dq + 1][qi] = t.y * 0.125f;
        Qs[dq + 2][qi] = t.z * 0.125f;
        Qs[dq + 3][qi] = t.w * 0.125f;
    }

    float o[4][4];
    #pragma unroll
    for (int i = 0; i < 4; ++i)
        #pragma unroll
        for (int j = 0; j < 4; ++j) o[i][j] = 0.f;
    float mOld[4] = {-1e30f, -1e30f, -1e30f, -1e30f};
    float lAcc[4] = {0.f, 0.f, 0.f, 0.f};

    for (int kt = 0; kt < Ss / 64; ++kt) {
        __syncthreads();   // prev iter done reading Ks(P) and Vs
        #pragma unroll
        for (int f = 0; f < 4; ++f) {
            int idx = tid + f * 256;
            int kj  = idx >> 4;
            int dq  = (idx & 15) << 2;
            size_t grow = (size_t)(bz * Ss + kt * 64 + kj) * 1024 + h * 64 + dq;
            float4 t = *(const float4*)&k[grow];
            Ks[dq + 0][kj] = t.x; Ks[dq + 1][kj] = t.y;
            Ks[dq + 2][kj] = t.z; Ks[dq + 3][kj] = t.w;
            float4 tv = *(const float4*)&v[grow];
            *(float4*)&Vs[kj][dq] = tv;
        }
        if (tid < 64) Ms[tid] = mask[bz * Ss + kt * 64 + tid];
        __syncthreads();

        // scores
        float sc[4][4];
        #pragma unroll
        for (int i = 0; i < 4; ++i)
            #pragma unroll
            for (int j = 0; j < 4; ++j) sc[i][j] = 0.f;
        for (int d = 0; d < 64; ++d) {
            float qa[4], kb[4];
            *(float4*)qa = *(const float4*)&Qs[d][ty4];
            *(float4*)kb = *(const float4*)&Ks[d][tx4];
            #pragma unroll
            for (int i = 0; i < 4; ++i)
                #pragma unroll
                for (int j = 0; j < 4; ++j)
                    sc[i][j] = fmaf(qa[i], kb[j], sc[i][j]);
        }

        bool mk[4];
        #pragma unroll
        for (int j = 0; j < 4; ++j) mk[j] = (Ms[tx4 + j] != 0);
        #pragma unroll
        for (int i = 0; i < 4; ++i)
            #pragma unroll
            for (int j = 0; j < 4; ++j)
                if (!mk[j]) sc[i][j] = -1e30f;

        float p[4][4];
        float rs[4];
        #pragma unroll
        for (int i = 0; i < 4; ++i) {
            float mr = fmaxf(fmaxf(sc[i][0], sc[i][1]), fmaxf(sc[i][2], sc[i][3]));
            #pragma unroll
            for (int off = 1; off < 16; off <<= 1) mr = fmaxf(mr, __shfl_xor(mr, off));
            float mn = fmaxf(mOld[i], mr);
            float r  = expf(mOld[i] - mn);
            float psum = 0.f;
            #pragma unroll
            for (int j = 0; j < 4; ++j) {
                p[i][j] = mk[j] ? expf(sc[i][j] - mn) : 0.f;
                psum += p[i][j];
            }
            #pragma unroll
            for (int off = 1; off < 16; off <<= 1) psum += __shfl_xor(psum, off);
            lAcc[i] = lAcc[i] * r + psum;
            mOld[i] = mn;
            rs[i]   = r;
        }
        #pragma unroll
        for (int i = 0; i < 4; ++i)
            #pragma unroll
            for (int j = 0; j < 4; ++j) o[i][j] *= rs[i];

        __syncthreads();   // everyone done reading Ks -> safe to overwrite with P
        #pragma unroll
        for (int j = 0; j < 4; ++j) {
            float4 pv = make_float4(p[0][j], p[1][j], p[2][j], p[3][j]);
            *(float4*)&Ks[tx4 + j][ty4] = pv;   // P[kj][qi]
        }
        __syncthreads();   // P ready

        for (int kj = 0; kj < 64; ++kj) {
            float pa[4], vb[4];
            *(float4*)pa = *(const float4*)&Ks[kj][ty4];
            *(float4*)vb = *(const float4*)&Vs[kj][tx4];
            #pragma unroll
            for (int i = 0; i < 4; ++i)
                #pragma unroll
                for (int j = 0; j < 4; ++j)
                    o[i][j] = fmaf(pa[i], vb[j], o[i][j]);
        }
    }

    #pragma unroll
    for (int i = 0; i < 4; ++i) {
        float inv = 1.0f / lAcc[i];
        int row = bz * Ss + qb * 64 + ty4 + i;
        float4 ov = make_float4(o[i][0] * inv, o[i][1] * inv, o[i][2] * inv, o[i][3] * inv);
        *(float4*)&ao[(size_t)row * 1024 + h * 64 + tx4] = ov;
    }
}

// ---------------- Output projection: fp32 store ----------------------------------
__global__ __launch_bounds__(256) void out_gemm_k(
    const float* __restrict__ ao, const float* __restrict__ Wo,
    const float* __restrict__ bo, float* __restrict__ out)
{
    __shared__ float As[16][128];
    __shared__ float Bs[16][128];
    const int bm = blockIdx.x * 128;
    const int n0 = blockIdx.y * 128;
    const int tid = threadIdx.x;
    const int tx = tid & 15;
    const int ty = tid >> 4;

    float acc[8][8];
    #pragma unroll
    for (int i = 0; i < 8; ++i)
        #pragma unroll
        for (int j = 0; j < 8; ++j) acc[i][j] = 0.f;

    for (int k0 = 0; k0 < 1024; k0 += 16) {
        __syncthreads();
        #pragma unroll
        for (int f = 0; f < 2; ++f) {
            int idx = tid + f * 256;
            int r   = idx >> 2;
            int kq  = (idx & 3) << 2;
            float4 av = *(const float4*)&ao[(size_t)(bm + r) * 1024 + k0 + kq];
            As[kq + 0][r] = av.x; As[kq + 1][r] = av.y;
            As[kq + 2][r] = av.z; As[kq + 3][r] = av.w;
            float4 wv = *(const float4*)&Wo[(size_t)(n0 + r) * 1024 + k0 + kq];
            Bs[kq + 0][r] = wv.x; Bs[kq + 1][r] = wv.y;
            Bs[kq + 2][r] = wv.z; Bs[kq + 3][r] = wv.w;
        }
        __syncthreads();
        #pragma unroll
        for (int kk = 0; kk < 16; ++kk) {
            float a[8], b[8];
            *(float4*)&a[0] = *(const float4*)&As[kk][ty * 8];
            *(float4*)&a[4] = *(const float4*)&As[kk][ty * 8 + 4];
            *(float4*)&b[0] = *(const float4*)&Bs[kk][tx * 8];
            *(float4*)&b[4] = *(const float4*)&Bs[kk][tx * 8 + 4];
            #pragma unroll
            for (int i = 0; i < 8; ++i)
                #pragma unroll
                for (int j = 0; j < 8; ++j)
                    acc[i][j] = fmaf(a[i], b[j], acc[i][j]);
        }
    }
    #pragma unroll
    for (int i = 0; i < 8; ++i) {
        const int row = bm + ty * 8 + i;
        float4 o0, o1;
        o0.x = acc[i][0] + bo[n0 + tx * 8 + 0];
        o0.y = acc[i][1] + bo[n0 + tx * 8 + 1];
        o0.z = acc[i][2] + bo[n0 + tx * 8 + 2];
        o0.w = acc[i][3] + bo[n0 + tx * 8 + 3];
        o1.x = acc[i][4] + bo[n0 + tx * 8 + 4];
        o1.y = acc[i][5] + bo[n0 + tx * 8 + 5];
        o1.z = acc[i][6] + bo[n0 + tx * 8 + 6];
        o1.w = acc[i][7] + bo[n0 + tx * 8 + 7];
        *(float4*)&out[(size_t)row * 1024 + n0 + tx * 8]     = o0;
        *(float4*)&out[(size_t)row * 1024 + n0 + tx * 8 + 4] = o1;
    }
}

extern "C" void kernel_launch(void* const* d_in, const int* in_sizes, int n_in,
                              void* d_out, int out_size, void* d_ws, size_t ws_size,
                              hipStream_t stream)
{
    const float* x  = (const float*)d_in[0];
    const int*   am = (const int*)d_in[1];
    const float* Wq = (const float*)d_in[2];
    const float* bq = (const float*)d_in[3];
    const float* Wk = (const float*)d_in[4];
    const float* bk = (const float*)d_in[5];
    const float* Wv = (const float*)d_in[6];
    const float* bv = (const float*)d_in[7];
    const float* Wo = (const float*)d_in[8];
    const float* bo = (const float*)d_in[9];
    float* out = (float*)d_out;

    float* q  = (float*)d_ws;
    float* k  = q + (size_t)Mm * Hh;
    float* v  = k + (size_t)Mm * Hh;
    float* ao = v + (size_t)Mm * Hh;

    qkv_gemm_k<<<dim3(Mm / 128, 3072 / 128), 256, 0, stream>>>(
        x, Wq, bq, Wk, bk, Wv, bv, q, k, v);
    rope_k<<<(Mm * 512) / 256, 256, 0, stream>>>(q, k);
    flash_k<<<dim3(Ss / 64, NHh, Bb), 256, 0, stream>>>(q, k, v, am, ao);
    out_gemm_k<<<dim3(Mm / 128, Hh / 128), 256, 0, stream>>>(ao, Wo, bo, out);
}

// Round 3
// 580.468 us; speedup vs baseline: 1.7447x; 1.7447x over previous
//
#include <hip/hip_runtime.h>
#include <hip/hip_bf16.h>

// GQA forward, round 2: bf16-MFMA flash attention; fp32 GEMMs (bf16 outputs for q/k/v).
// B=2, S=2048, HIDDEN=1024, 16 heads x 64 dim, RoPE over full hidden (half=512).
// ws: q,k,v bf16 (24MB) + ao fp32 (16MB) = 40MB.

constexpr int Bb  = 2;
constexpr int Ss  = 2048;
constexpr int Hh  = 1024;
constexpr int NHh = 16;
constexpr int Mm  = Bb * Ss;   // 4096 rows

typedef __attribute__((ext_vector_type(8))) unsigned short ushort8;
typedef __attribute__((ext_vector_type(4))) unsigned short ushort4_t;
typedef __attribute__((ext_vector_type(8))) short short8;
typedef __attribute__((ext_vector_type(4))) float f32x4;

__device__ __forceinline__ unsigned short f2bf(float f) {
    unsigned int u = __float_as_uint(f);
    u += 0x7fffu + ((u >> 16) & 1u);
    return (unsigned short)(u >> 16);
}
__device__ __forceinline__ float bf2f(unsigned short h) {
    return __uint_as_float(((unsigned int)h) << 16);
}

// ---------------- QKV projection (fp32 compute, bf16 store) ----------------------
__global__ __launch_bounds__(256) void qkv_gemm_k(
    const float* __restrict__ x,
    const float* __restrict__ Wq, const float* __restrict__ bq,
    const float* __restrict__ Wk, const float* __restrict__ bk,
    const float* __restrict__ Wv, const float* __restrict__ bv,
    unsigned short* __restrict__ q, unsigned short* __restrict__ k,
    unsigned short* __restrict__ v)
{
    __shared__ float As[16][128];
    __shared__ float Bs[16][128];
    const int bm = blockIdx.x * 128;
    const int gn = blockIdx.y * 128;

    const float* W; const float* bias; unsigned short* outp; int n0;
    if (gn < 1024)      { W = Wq; bias = bq; outp = q; n0 = gn; }
    else if (gn < 2048) { W = Wk; bias = bk; outp = k; n0 = gn - 1024; }
    else                { W = Wv; bias = bv; outp = v; n0 = gn - 2048; }

    const int tid = threadIdx.x;
    const int tx = tid & 15;
    const int ty = tid >> 4;

    float acc[8][8];
    #pragma unroll
    for (int i = 0; i < 8; ++i)
        #pragma unroll
        for (int j = 0; j < 8; ++j) acc[i][j] = 0.f;

    for (int k0 = 0; k0 < 1024; k0 += 16) {
        __syncthreads();
        #pragma unroll
        for (int f = 0; f < 2; ++f) {
            int idx = tid + f * 256;
            int r   = idx >> 2;
            int kq  = (idx & 3) << 2;
            float4 av = *(const float4*)&x[(size_t)(bm + r) * 1024 + k0 + kq];
            As[kq + 0][r] = av.x; As[kq + 1][r] = av.y;
            As[kq + 2][r] = av.z; As[kq + 3][r] = av.w;
            float4 wv = *(const float4*)&W[(size_t)(n0 + r) * 1024 + k0 + kq];
            Bs[kq + 0][r] = wv.x; Bs[kq + 1][r] = wv.y;
            Bs[kq + 2][r] = wv.z; Bs[kq + 3][r] = wv.w;
        }
        __syncthreads();
        #pragma unroll
        for (int kk = 0; kk < 16; ++kk) {
            float a[8], b[8];
            *(float4*)&a[0] = *(const float4*)&As[kk][ty * 8];
            *(float4*)&a[4] = *(const float4*)&As[kk][ty * 8 + 4];
            *(float4*)&b[0] = *(const float4*)&Bs[kk][tx * 8];
            *(float4*)&b[4] = *(const float4*)&Bs[kk][tx * 8 + 4];
            #pragma unroll
            for (int i = 0; i < 8; ++i)
                #pragma unroll
                for (int j = 0; j < 8; ++j)
                    acc[i][j] = fmaf(a[i], b[j], acc[i][j]);
        }
    }
    #pragma unroll
    for (int i = 0; i < 8; ++i) {
        const int row = bm + ty * 8 + i;
        ushort8 ov;
        #pragma unroll
        for (int j = 0; j < 8; ++j)
            ov[j] = f2bf(acc[i][j] + bias[n0 + tx * 8 + j]);
        *(ushort8*)&outp[(size_t)row * 1024 + n0 + tx * 8] = ov;
    }
}

// ---------------- RoPE on bf16: pair (j, j+512), 4 pairs per thread --------------
__global__ __launch_bounds__(256) void rope_k(
    unsigned short* __restrict__ q, unsigned short* __restrict__ kk)
{
    int idx = blockIdx.x * 256 + threadIdx.x;   // Mm*128 threads total
    int row = idx >> 7;
    int j4  = (idx & 127) << 2;
    int pos = row & (Ss - 1);
    size_t base = (size_t)row * 1024;

    ushort4_t qa = *(ushort4_t*)&q[base + j4];
    ushort4_t qb = *(ushort4_t*)&q[base + 512 + j4];
    ushort4_t ka = *(ushort4_t*)&kk[base + j4];
    ushort4_t kb = *(ushort4_t*)&kk[base + 512 + j4];

    #pragma unroll
    for (int t = 0; t < 4; ++t) {
        float jj = (float)(j4 + t);
        float inv = exp2f(jj * -0.0259525632621414f);  // 10000^(-j/512)
        float ang = (float)pos * inv;
        float sn, cs;
        __sincosf(ang, &sn, &cs);
        float a = bf2f(qa[t]), b = bf2f(qb[t]);
        qa[t] = f2bf(a * cs - b * sn);
        qb[t] = f2bf(b * cs + a * sn);
        float c = bf2f(ka[t]), d = bf2f(kb[t]);
        ka[t] = f2bf(c * cs - d * sn);
        kb[t] = f2bf(d * cs + c * sn);
    }
    *(ushort4_t*)&q[base + j4]        = qa;
    *(ushort4_t*)&q[base + 512 + j4]  = qb;
    *(ushort4_t*)&kk[base + j4]       = ka;
    *(ushort4_t*)&kk[base + 512 + j4] = kb;
}

// ---------------- Flash attention, bf16 MFMA 16x16x32 ----------------------------
// Block: 256 thr = 4 waves; wave handles 32 queries (2 MFMA q-tiles); block 128 q.
// KV tile = 64 keys. LDS: K[64][64] + Vt[64][64] + P[4][32][64], all XOR-swizzled.
__global__ __launch_bounds__(256) void flash_k(
    const unsigned short* __restrict__ q, const unsigned short* __restrict__ k,
    const unsigned short* __restrict__ v, const int* __restrict__ mask,
    float* __restrict__ ao)
{
    __shared__ unsigned short Ks[64 * 64];
    __shared__ unsigned short Vt[64 * 64];
    __shared__ unsigned short Pb[4][32 * 64];

    const int qb   = blockIdx.x;      // 16
    const int h    = blockIdx.y;      // 16
    const int bz   = blockIdx.z;      // 2
    const int tid  = threadIdx.x;
    const int lane = tid & 63;
    const int w    = tid >> 6;
    const int l16  = lane & 15;
    const int g    = lane >> 4;       // 0..3
    const int sw   = (lane & 7) << 4; // XOR swizzle key for reads (row&7 == lane&7)

    char* ksb = (char*)&Ks[0];
    char* vtb = (char*)&Vt[0];
    char* pbb = (char*)&Pb[w][0];

    const int qrowbase = bz * Ss + qb * 128 + w * 32;

    // Q fragments (held whole loop): [qtile][dstep], lane l = Q[q=l16][d=g*8+e]
    short8 qf[2][2];
    #pragma unroll
    for (int t = 0; t < 2; ++t)
        #pragma unroll
        for (int s = 0; s < 2; ++s)
            qf[t][s] = *(const short8*)&q[(size_t)(qrowbase + t * 16 + l16) * 1024
                                          + h * 64 + s * 32 + g * 8];

    f32x4 O[2][4];
    #pragma unroll
    for (int t = 0; t < 2; ++t)
        #pragma unroll
        for (int d = 0; d < 4; ++d) O[t][d] = (f32x4)0.f;
    float mrow[2][4], lsum[2][4];
    #pragma unroll
    for (int t = 0; t < 2; ++t)
        #pragma unroll
        for (int r = 0; r < 4; ++r) { mrow[t][r] = -1e30f; lsum[t][r] = 0.f; }

    const float SCALE = 0.18033688011112042f;  // (1/8) * log2(e)

    for (int kt = 0; kt < Ss / 64; ++kt) {
        // ---- stage K (row-major, swizzled) ----
        #pragma unroll
        for (int c0 = 0; c0 < 2; ++c0) {
            int c   = tid + c0 * 256;
            int row = c >> 3;
            int off = (c & 7) << 3;
            ushort8 t8 = *(const ushort8*)&k[(size_t)(bz * Ss + kt * 64 + row) * 1024
                                             + h * 64 + off];
            *(ushort8*)(ksb + row * 128 + ((off * 2) ^ ((row & 7) << 4))) = t8;
        }
        // ---- stage V transposed (Vt[d][k], swizzled) ----
        {
            int kv    = tid & 63;
            int dbase = (tid >> 6) << 4;
            #pragma unroll
            for (int half = 0; half < 2; ++half) {
                int d0 = dbase + half * 8;
                ushort8 t8 = *(const ushort8*)&v[(size_t)(bz * Ss + kt * 64 + kv) * 1024
                                                 + h * 64 + d0];
                #pragma unroll
                for (int jj = 0; jj < 8; ++jj) {
                    int d = d0 + jj;
                    *(unsigned short*)(vtb + d * 128 + ((kv * 2) ^ ((d & 7) << 4))) = t8[jj];
                }
            }
        }
        __syncthreads();

        // ---- QK^T ----
        f32x4 S[2][4];
        #pragma unroll
        for (int t = 0; t < 2; ++t)
            #pragma unroll
            for (int kt4 = 0; kt4 < 4; ++kt4) S[t][kt4] = (f32x4)0.f;

        #pragma unroll
        for (int kt4 = 0; kt4 < 4; ++kt4) {
            int key = kt4 * 16 + l16;
            short8 kf0 = *(const short8*)(ksb + key * 128 + ((g * 16) ^ sw));
            short8 kf1 = *(const short8*)(ksb + key * 128 + ((64 + g * 16) ^ sw));
            #pragma unroll
            for (int t = 0; t < 2; ++t) {
                S[t][kt4] = __builtin_amdgcn_mfma_f32_16x16x32_bf16(qf[t][0], kf0, S[t][kt4], 0, 0, 0);
                S[t][kt4] = __builtin_amdgcn_mfma_f32_16x16x32_bf16(qf[t][1], kf1, S[t][kt4], 0, 0, 0);
            }
        }

        // ---- mask + scale ----
        int mk4[4];
        #pragma unroll
        for (int kt4 = 0; kt4 < 4; ++kt4)
            mk4[kt4] = mask[bz * Ss + kt * 64 + kt4 * 16 + l16];
        #pragma unroll
        for (int t = 0; t < 2; ++t)
            #pragma unroll
            for (int kt4 = 0; kt4 < 4; ++kt4)
                #pragma unroll
                for (int r = 0; r < 4; ++r)
                    S[t][kt4][r] = mk4[kt4] ? S[t][kt4][r] * SCALE : -1e30f;

        // ---- online softmax (log2 domain) ----
        #pragma unroll
        for (int t = 0; t < 2; ++t) {
            #pragma unroll
            for (int r = 0; r < 4; ++r) {
                float rm = fmaxf(fmaxf(S[t][0][r], S[t][1][r]), fmaxf(S[t][2][r], S[t][3][r]));
                rm = fmaxf(rm, __shfl_xor(rm, 1));
                rm = fmaxf(rm, __shfl_xor(rm, 2));
                rm = fmaxf(rm, __shfl_xor(rm, 4));
                rm = fmaxf(rm, __shfl_xor(rm, 8));
                float mn = fmaxf(mrow[t][r], rm);
                float rs = exp2f(mrow[t][r] - mn);
                mrow[t][r] = mn;
                float psum = 0.f;
                #pragma unroll
                for (int kt4 = 0; kt4 < 4; ++kt4) {
                    float p = exp2f(S[t][kt4][r] - mn);
                    S[t][kt4][r] = p;
                    psum += p;
                }
                psum += __shfl_xor(psum, 1);
                psum += __shfl_xor(psum, 2);
                psum += __shfl_xor(psum, 4);
                psum += __shfl_xor(psum, 8);
                lsum[t][r] = lsum[t][r] * rs + psum;
                #pragma unroll
                for (int d = 0; d < 4; ++d) O[t][d][r] *= rs;
            }
        }

        // ---- write P (bf16) to per-wave LDS ----
        #pragma unroll
        for (int t = 0; t < 2; ++t)
            #pragma unroll
            for (int kt4 = 0; kt4 < 4; ++kt4)
                #pragma unroll
                for (int r = 0; r < 4; ++r) {
                    int prow = t * 16 + g * 4 + r;
                    int pcol = kt4 * 16 + l16;
                    *(unsigned short*)(pbb + prow * 128 + ((pcol * 2) ^ ((prow & 7) << 4)))
                        = f2bf(S[t][kt4][r]);
                }

        // ---- PV ----
        #pragma unroll
        for (int ks = 0; ks < 2; ++ks) {
            short8 pf[2];
            #pragma unroll
            for (int t = 0; t < 2; ++t)
                pf[t] = *(const short8*)(pbb + (t * 16 + l16) * 128 + ((ks * 64 + g * 16) ^ sw));
            #pragma unroll
            for (int dt = 0; dt < 4; ++dt) {
                short8 vf = *(const short8*)(vtb + (dt * 16 + l16) * 128 + ((ks * 64 + g * 16) ^ sw));
                #pragma unroll
                for (int t = 0; t < 2; ++t)
                    O[t][dt] = __builtin_amdgcn_mfma_f32_16x16x32_bf16(pf[t], vf, O[t][dt], 0, 0, 0);
            }
        }
        __syncthreads();
    }

    // ---- epilogue: normalize, store fp32 ----
    #pragma unroll
    for (int t = 0; t < 2; ++t)
        #pragma unroll
        for (int r = 0; r < 4; ++r) {
            float inv = 1.0f / lsum[t][r];
            int row = qrowbase + t * 16 + g * 4 + r;
            #pragma unroll
            for (int dt = 0; dt < 4; ++dt)
                ao[(size_t)row * 1024 + h * 64 + dt * 16 + l16] = O[t][dt][r] * inv;
        }
}

// ---------------- Output projection (fp32), fp32 store ---------------------------
__global__ __launch_bounds__(256) void out_gemm_k(
    const float* __restrict__ ao, const float* __restrict__ Wo,
    const float* __restrict__ bo, float* __restrict__ out)
{
    __shared__ float As[16][128];
    __shared__ float Bs[16][128];
    const int bm = blockIdx.x * 128;
    const int n0 = blockIdx.y * 128;
    const int tid = threadIdx.x;
    const int tx = tid & 15;
    const int ty = tid >> 4;

    float acc[8][8];
    #pragma unroll
    for (int i = 0; i < 8; ++i)
        #pragma unroll
        for (int j = 0; j < 8; ++j) acc[i][j] = 0.f;

    for (int k0 = 0; k0 < 1024; k0 += 16) {
        __syncthreads();
        #pragma unroll
        for (int f = 0; f < 2; ++f) {
            int idx = tid + f * 256;
            int r   = idx >> 2;
            int kq  = (idx & 3) << 2;
            float4 av = *(const float4*)&ao[(size_t)(bm + r) * 1024 + k0 + kq];
            As[kq + 0][r] = av.x; As[kq + 1][r] = av.y;
            As[kq + 2][r] = av.z; As[kq + 3][r] = av.w;
            float4 wv = *(const float4*)&Wo[(size_t)(n0 + r) * 1024 + k0 + kq];
            Bs[kq + 0][r] = wv.x; Bs[kq + 1][r] = wv.y;
            Bs[kq + 2][r] = wv.z; Bs[kq + 3][r] = wv.w;
        }
        __syncthreads();
        #pragma unroll
        for (int kk = 0; kk < 16; ++kk) {
            float a[8], b[8];
            *(float4*)&a[0] = *(const float4*)&As[kk][ty * 8];
            *(float4*)&a[4] = *(const float4*)&As[kk][ty * 8 + 4];
            *(float4*)&b[0] = *(const float4*)&Bs[kk][tx * 8];
            *(float4*)&b[4] = *(const float4*)&Bs[kk][tx * 8 + 4];
            #pragma unroll
            for (int i = 0; i < 8; ++i)
                #pragma unroll
                for (int j = 0; j < 8; ++j)
                    acc[i][j] = fmaf(a[i], b[j], acc[i][j]);
        }
    }
    #pragma unroll
    for (int i = 0; i < 8; ++i) {
        const int row = bm + ty * 8 + i;
        float4 o0, o1;
        o0.x = acc[i][0] + bo[n0 + tx * 8 + 0];
        o0.y = acc[i][1] + bo[n0 + tx * 8 + 1];
        o0.z = acc[i][2] + bo[n0 + tx * 8 + 2];
        o0.w = acc[i][3] + bo[n0 + tx * 8 + 3];
        o1.x = acc[i][4] + bo[n0 + tx * 8 + 4];
        o1.y = acc[i][5] + bo[n0 + tx * 8 + 5];
        o1.z = acc[i][6] + bo[n0 + tx * 8 + 6];
        o1.w = acc[i][7] + bo[n0 + tx * 8 + 7];
        *(float4*)&out[(size_t)row * 1024 + n0 + tx * 8]     = o0;
        *(float4*)&out[(size_t)row * 1024 + n0 + tx * 8 + 4] = o1;
    }
}

extern "C" void kernel_launch(void* const* d_in, const int* in_sizes, int n_in,
                              void* d_out, int out_size, void* d_ws, size_t ws_size,
                              hipStream_t stream)
{
    const float* x  = (const float*)d_in[0];
    const int*   am = (const int*)d_in[1];
    const float* Wq = (const float*)d_in[2];
    const float* bq = (const float*)d_in[3];
    const float* Wk = (const float*)d_in[4];
    const float* bk = (const float*)d_in[5];
    const float* Wv = (const float*)d_in[6];
    const float* bv = (const float*)d_in[7];
    const float* Wo = (const float*)d_in[8];
    const float* bo = (const float*)d_in[9];
    float* out = (float*)d_out;

    unsigned short* q = (unsigned short*)d_ws;
    unsigned short* k = q + (size_t)Mm * Hh;
    unsigned short* v = k + (size_t)Mm * Hh;
    float*          ao = (float*)(v + (size_t)Mm * Hh);

    qkv_gemm_k<<<dim3(Mm / 128, 3072 / 128), 256, 0, stream>>>(
        x, Wq, bq, Wk, bk, Wv, bv, q, k, v);
    rope_k<<<(Mm * 128) / 256, 256, 0, stream>>>(q, k);
    flash_k<<<dim3(Ss / 128, NHh, Bb), 256, 0, stream>>>(q, k, v, am, ao);
    out_gemm_k<<<dim3(Mm / 128, Hh / 128), 256, 0, stream>>>(ao, Wo, bo, out);
}

// Round 4
// 222.162 us; speedup vs baseline: 4.5585x; 2.6128x over previous
//
#include <hip/hip_runtime.h>
#include <hip/hip_bf16.h>

// GQA forward, round 3: bf16 MFMA everywhere (QKV GEMM, flash attn, out GEMM).
// B=2, S=2048, HIDDEN=1024, 16 heads x 64 dim, RoPE over full hidden (half=512).
// ws layout (ushort elems): q(4M) k(4M) v(4M) ao(4M) xb(4M) wall(4M) = 48 MB.

constexpr int Bb  = 2;
constexpr int Ss  = 2048;
constexpr int Hh  = 1024;
constexpr int NHh = 16;
constexpr int Mm  = Bb * Ss;   // 4096 rows

typedef __attribute__((ext_vector_type(8))) unsigned short ushort8;
typedef __attribute__((ext_vector_type(4))) unsigned short ushort4_t;
typedef __attribute__((ext_vector_type(8))) short short8;
typedef __attribute__((ext_vector_type(4))) float f32x4;

__device__ __forceinline__ unsigned short f2bf(float f) {
    unsigned int u = __float_as_uint(f);
    u += 0x7fffu + ((u >> 16) & 1u);
    return (unsigned short)(u >> 16);
}
__device__ __forceinline__ float bf2f(unsigned short h) {
    return __uint_as_float(((unsigned int)h) << 16);
}
__device__ __forceinline__ void gload16(const void* g, void* l) {
    __builtin_amdgcn_global_load_lds(
        (const __attribute__((address_space(1))) unsigned int*)g,
        (__attribute__((address_space(3))) unsigned int*)l, 16, 0, 0);
}

// ---------------- fp32 -> bf16 convert (x, Wq|Wk|Wv|Wo into one block) ----------
__global__ __launch_bounds__(256) void convert_k(
    const float* __restrict__ x,
    const float* __restrict__ Wq, const float* __restrict__ Wk,
    const float* __restrict__ Wv, const float* __restrict__ Wo,
    unsigned short* __restrict__ xb, unsigned short* __restrict__ wall)
{
    size_t e = ((size_t)blockIdx.x * 256 + threadIdx.x) << 3;
    const float* s; unsigned short* d;
    if (e < (size_t)Mm * Hh) {
        s = x + e; d = xb + e;
    } else {
        size_t f = e - (size_t)Mm * Hh;
        int t = (int)(f >> 20);
        const float* w = (t == 0) ? Wq : (t == 1) ? Wk : (t == 2) ? Wv : Wo;
        s = w + (f & 1048575);
        d = wall + f;
    }
    float4 a = *(const float4*)s;
    float4 b = *(const float4*)(s + 4);
    ushort8 o;
    o[0] = f2bf(a.x); o[1] = f2bf(a.y); o[2] = f2bf(a.z); o[3] = f2bf(a.w);
    o[4] = f2bf(b.x); o[5] = f2bf(b.y); o[6] = f2bf(b.z); o[7] = f2bf(b.w);
    *(ushort8*)d = o;
}

// ---------------- bf16 MFMA GEMM core: C[128x128] = A[128xK] . W[128 rows][K] ----
// 256 thr = 4 waves (2x2), BK=64, global_load_lds w=16 with pre-swizzled source,
// XOR-swizzled ds_read_b128 fragments (byte ^= (row&7)<<4 within 128B row).
#define GEMM_BODY(ATYPE_PTR, WPTR, K0MAX)                                          \
    __shared__ unsigned short As[128 * 64];                                        \
    __shared__ unsigned short Bs[128 * 64];                                        \
    const int tid  = threadIdx.x;                                                  \
    const int lane = tid & 63;                                                     \
    const int w    = tid >> 6;                                                     \
    const int wr   = w >> 1, wc = w & 1;                                           \
    const int l16  = lane & 15, g = lane >> 4;                                     \
    const int R0   = blockIdx.x * 128;                                             \
    char* asb = (char*)As; char* bsb = (char*)Bs;                                  \
    f32x4 acc[4][4] = {};                                                          \
    for (int k0 = 0; k0 < K0MAX; k0 += 64) {                                       \
        _Pragma("unroll")                                                          \
        for (int it = 0; it < 4; ++it) {                                           \
            int sbase = w * 4096 + it * 1024;                                      \
            int boff  = sbase + lane * 16;                                         \
            int r     = boff >> 7;                                                 \
            int c     = (boff >> 4) & 7;                                           \
            int col   = k0 + ((c ^ (r & 7)) << 3);                                 \
            gload16(&ATYPE_PTR[(size_t)(R0 + r) * 1024 + col], asb + sbase);       \
            gload16(&WPTR[(size_t)(gn + r) * 1024 + col], bsb + sbase);            \
        }                                                                          \
        __syncthreads();                                                           \
        short8 bfrag[4][2];                                                        \
        _Pragma("unroll")                                                          \
        for (int u = 0; u < 4; ++u) {                                              \
            int row = wc * 64 + u * 16 + l16;                                      \
            _Pragma("unroll")                                                      \
            for (int s = 0; s < 2; ++s)                                            \
                bfrag[u][s] = *(const short8*)(bsb + row * 128 +                   \
                               ((s * 64 + g * 16) ^ ((row & 7) << 4)));            \
        }                                                                          \
        _Pragma("unroll")                                                          \
        for (int t = 0; t < 4; ++t) {                                              \
            int row = wr * 64 + t * 16 + l16;                                      \
            short8 af[2];                                                          \
            _Pragma("unroll")                                                      \
            for (int s = 0; s < 2; ++s)                                            \
                af[s] = *(const short8*)(asb + row * 128 +                         \
                         ((s * 64 + g * 16) ^ ((row & 7) << 4)));                  \
            _Pragma("unroll")                                                      \
            for (int u = 0; u < 4; ++u) {                                          \
                acc[t][u] = __builtin_amdgcn_mfma_f32_16x16x32_bf16(af[0], bfrag[u][0], acc[t][u], 0, 0, 0); \
                acc[t][u] = __builtin_amdgcn_mfma_f32_16x16x32_bf16(af[1], bfrag[u][1], acc[t][u], 0, 0, 0); \
            }                                                                      \
        }                                                                          \
        __syncthreads();                                                           \
    }

// ---------------- QKV projection (bf16 MFMA), bf16 out, bias fused ---------------
__global__ __launch_bounds__(256) void gemm_qkv_k(
    const unsigned short* __restrict__ xb, const unsigned short* __restrict__ wall,
    const float* __restrict__ bq, const float* __restrict__ bk, const float* __restrict__ bv,
    unsigned short* __restrict__ q, unsigned short* __restrict__ k2,
    unsigned short* __restrict__ v)
{
    const int gn = blockIdx.y * 128;     // 0..2944, W row base in wall
    GEMM_BODY(xb, wall, 1024)

    const int sel = gn >> 10;
    const int n0  = gn & 1023;
    const float* bias = (sel == 0) ? bq : (sel == 1) ? bk : bv;
    unsigned short* outp = (sel == 0) ? q : (sel == 1) ? k2 : v;
    #pragma unroll
    for (int u = 0; u < 4; ++u) {
        int coll = wc * 64 + u * 16 + l16;
        float bb = bias[n0 + coll];
        #pragma unroll
        for (int t = 0; t < 4; ++t)
            #pragma unroll
            for (int rr = 0; rr < 4; ++rr) {
                int row = R0 + wr * 64 + t * 16 + g * 4 + rr;
                outp[(size_t)row * 1024 + n0 + coll] = f2bf(acc[t][u][rr] + bb);
            }
    }
}

// ---------------- Output projection (bf16 MFMA), fp32 out, bias fused ------------
__global__ __launch_bounds__(256) void gemm_out_k(
    const unsigned short* __restrict__ ao, const unsigned short* __restrict__ wo,
    const float* __restrict__ bo, float* __restrict__ out)
{
    const int gn = blockIdx.y * 128;
    GEMM_BODY(ao, wo, 1024)

    #pragma unroll
    for (int u = 0; u < 4; ++u) {
        int coll = wc * 64 + u * 16 + l16;
        float bb = bo[gn + coll];
        #pragma unroll
        for (int t = 0; t < 4; ++t)
            #pragma unroll
            for (int rr = 0; rr < 4; ++rr) {
                int row = R0 + wr * 64 + t * 16 + g * 4 + rr;
                out[(size_t)row * 1024 + gn + coll] = acc[t][u][rr] + bb;
            }
    }
}

// ---------------- RoPE on bf16: pair (j, j+512), 4 pairs per thread --------------
__global__ __launch_bounds__(256) void rope_k(
    unsigned short* __restrict__ q, unsigned short* __restrict__ kk)
{
    int idx = blockIdx.x * 256 + threadIdx.x;   // Mm*128 threads total
    int row = idx >> 7;
    int j4  = (idx & 127) << 2;
    int pos = row & (Ss - 1);
    size_t base = (size_t)row * 1024;

    ushort4_t qa = *(ushort4_t*)&q[base + j4];
    ushort4_t qb = *(ushort4_t*)&q[base + 512 + j4];
    ushort4_t ka = *(ushort4_t*)&kk[base + j4];
    ushort4_t kb = *(ushort4_t*)&kk[base + 512 + j4];

    #pragma unroll
    for (int t = 0; t < 4; ++t) {
        float jj = (float)(j4 + t);
        float inv = exp2f(jj * -0.0259525632621414f);  // 10000^(-j/512)
        float ang = (float)pos * inv;
        float sn, cs;
        __sincosf(ang, &sn, &cs);
        float a = bf2f(qa[t]), b = bf2f(qb[t]);
        qa[t] = f2bf(a * cs - b * sn);
        qb[t] = f2bf(b * cs + a * sn);
        float c = bf2f(ka[t]), d = bf2f(kb[t]);
        ka[t] = f2bf(c * cs - d * sn);
        kb[t] = f2bf(d * cs + c * sn);
    }
    *(ushort4_t*)&q[base + j4]        = qa;
    *(ushort4_t*)&q[base + 512 + j4]  = qb;
    *(ushort4_t*)&kk[base + j4]       = ka;
    *(ushort4_t*)&kk[base + 512 + j4] = kb;
}

// ---------------- Flash attention, bf16 MFMA 16x16x32 ----------------------------
__global__ __launch_bounds__(256) void flash_k(
    const unsigned short* __restrict__ q, const unsigned short* __restrict__ k,
    const unsigned short* __restrict__ v, const int* __restrict__ mask,
    unsigned short* __restrict__ ao)
{
    __shared__ unsigned short Ks[64 * 64];
    __shared__ unsigned short Vt[64 * 64];
    __shared__ unsigned short Pb[4][32 * 64];

    const int qb   = blockIdx.x;      // 16
    const int h    = blockIdx.y;      // 16
    const int bz   = blockIdx.z;      // 2
    const int tid  = threadIdx.x;
    const int lane = tid & 63;
    const int w    = tid >> 6;
    const int l16  = lane & 15;
    const int g    = lane >> 4;       // 0..3
    const int sw   = (lane & 7) << 4;

    char* ksb = (char*)&Ks[0];
    char* vtb = (char*)&Vt[0];
    char* pbb = (char*)&Pb[w][0];

    const int qrowbase = bz * Ss + qb * 128 + w * 32;

    short8 qf[2][2];
    #pragma unroll
    for (int t = 0; t < 2; ++t)
        #pragma unroll
        for (int s = 0; s < 2; ++s)
            qf[t][s] = *(const short8*)&q[(size_t)(qrowbase + t * 16 + l16) * 1024
                                          + h * 64 + s * 32 + g * 8];

    f32x4 O[2][4];
    #pragma unroll
    for (int t = 0; t < 2; ++t)
        #pragma unroll
        for (int d = 0; d < 4; ++d) O[t][d] = (f32x4)0.f;
    float mrow[2][4], lsum[2][4];
    #pragma unroll
    for (int t = 0; t < 2; ++t)
        #pragma unroll
        for (int r = 0; r < 4; ++r) { mrow[t][r] = -1e30f; lsum[t][r] = 0.f; }

    const float SCALE = 0.18033688011112042f;  // (1/8) * log2(e)

    for (int kt = 0; kt < Ss / 64; ++kt) {
        #pragma unroll
        for (int c0 = 0; c0 < 2; ++c0) {
            int c   = tid + c0 * 256;
            int row = c >> 3;
            int off = (c & 7) << 3;
            ushort8 t8 = *(const ushort8*)&k[(size_t)(bz * Ss + kt * 64 + row) * 1024
                                             + h * 64 + off];
            *(ushort8*)(ksb + row * 128 + ((off * 2) ^ ((row & 7) << 4))) = t8;
        }
        {
            int kv    = tid & 63;
            int dbase = (tid >> 6) << 4;
            #pragma unroll
            for (int half = 0; half < 2; ++half) {
                int d0 = dbase + half * 8;
                ushort8 t8 = *(const ushort8*)&v[(size_t)(bz * Ss + kt * 64 + kv) * 1024
                                                 + h * 64 + d0];
                #pragma unroll
                for (int jj = 0; jj < 8; ++jj) {
                    int d = d0 + jj;
                    *(unsigned short*)(vtb + d * 128 + ((kv * 2) ^ ((d & 7) << 4))) = t8[jj];
                }
            }
        }
        __syncthreads();

        f32x4 S[2][4];
        #pragma unroll
        for (int t = 0; t < 2; ++t)
            #pragma unroll
            for (int kt4 = 0; kt4 < 4; ++kt4) S[t][kt4] = (f32x4)0.f;

        #pragma unroll
        for (int kt4 = 0; kt4 < 4; ++kt4) {
            int key = kt4 * 16 + l16;
            short8 kf0 = *(const short8*)(ksb + key * 128 + ((g * 16) ^ sw));
            short8 kf1 = *(const short8*)(ksb + key * 128 + ((64 + g * 16) ^ sw));
            #pragma unroll
            for (int t = 0; t < 2; ++t) {
                S[t][kt4] = __builtin_amdgcn_mfma_f32_16x16x32_bf16(qf[t][0], kf0, S[t][kt4], 0, 0, 0);
                S[t][kt4] = __builtin_amdgcn_mfma_f32_16x16x32_bf16(qf[t][1], kf1, S[t][kt4], 0, 0, 0);
            }
        }

        int mk4[4];
        #pragma unroll
        for (int kt4 = 0; kt4 < 4; ++kt4)
            mk4[kt4] = mask[bz * Ss + kt * 64 + kt4 * 16 + l16];
        #pragma unroll
        for (int t = 0; t < 2; ++t)
            #pragma unroll
            for (int kt4 = 0; kt4 < 4; ++kt4)
                #pragma unroll
                for (int r = 0; r < 4; ++r)
                    S[t][kt4][r] = mk4[kt4] ? S[t][kt4][r] * SCALE : -1e30f;

        #pragma unroll
        for (int t = 0; t < 2; ++t) {
            #pragma unroll
            for (int r = 0; r < 4; ++r) {
                float rm = fmaxf(fmaxf(S[t][0][r], S[t][1][r]), fmaxf(S[t][2][r], S[t][3][r]));
                rm = fmaxf(rm, __shfl_xor(rm, 1));
                rm = fmaxf(rm, __shfl_xor(rm, 2));
                rm = fmaxf(rm, __shfl_xor(rm, 4));
                rm = fmaxf(rm, __shfl_xor(rm, 8));
                float mn = fmaxf(mrow[t][r], rm);
                float rs = exp2f(mrow[t][r] - mn);
                mrow[t][r] = mn;
                float psum = 0.f;
                #pragma unroll
                for (int kt4 = 0; kt4 < 4; ++kt4) {
                    float p = exp2f(S[t][kt4][r] - mn);
                    S[t][kt4][r] = p;
                    psum += p;
                }
                psum += __shfl_xor(psum, 1);
                psum += __shfl_xor(psum, 2);
                psum += __shfl_xor(psum, 4);
                psum += __shfl_xor(psum, 8);
                lsum[t][r] = lsum[t][r] * rs + psum;
                #pragma unroll
                for (int d = 0; d < 4; ++d) O[t][d][r] *= rs;
            }
        }

        #pragma unroll
        for (int t = 0; t < 2; ++t)
            #pragma unroll
            for (int kt4 = 0; kt4 < 4; ++kt4)
                #pragma unroll
                for (int r = 0; r < 4; ++r) {
                    int prow = t * 16 + g * 4 + r;
                    int pcol = kt4 * 16 + l16;
                    *(unsigned short*)(pbb + prow * 128 + ((pcol * 2) ^ ((prow & 7) << 4)))
                        = f2bf(S[t][kt4][r]);
                }

        #pragma unroll
        for (int ks = 0; ks < 2; ++ks) {
            short8 pf[2];
            #pragma unroll
            for (int t = 0; t < 2; ++t)
                pf[t] = *(const short8*)(pbb + (t * 16 + l16) * 128 + ((ks * 64 + g * 16) ^ sw));
            #pragma unroll
            for (int dt = 0; dt < 4; ++dt) {
                short8 vf = *(const short8*)(vtb + (dt * 16 + l16) * 128 + ((ks * 64 + g * 16) ^ sw));
                #pragma unroll
                for (int t = 0; t < 2; ++t)
                    O[t][dt] = __builtin_amdgcn_mfma_f32_16x16x32_bf16(pf[t], vf, O[t][dt], 0, 0, 0);
            }
        }
        __syncthreads();
    }

    #pragma unroll
    for (int t = 0; t < 2; ++t)
        #pragma unroll
        for (int r = 0; r < 4; ++r) {
            float inv = 1.0f / lsum[t][r];
            int row = qrowbase + t * 16 + g * 4 + r;
            #pragma unroll
            for (int dt = 0; dt < 4; ++dt)
                ao[(size_t)row * 1024 + h * 64 + dt * 16 + l16] = f2bf(O[t][dt][r] * inv);
        }
}

extern "C" void kernel_launch(void* const* d_in, const int* in_sizes, int n_in,
                              void* d_out, int out_size, void* d_ws, size_t ws_size,
                              hipStream_t stream)
{
    const float* x  = (const float*)d_in[0];
    const int*   am = (const int*)d_in[1];
    const float* Wq = (const float*)d_in[2];
    const float* bq = (const float*)d_in[3];
    const float* Wk = (const float*)d_in[4];
    const float* bk = (const float*)d_in[5];
    const float* Wv = (const float*)d_in[6];
    const float* bv = (const float*)d_in[7];
    const float* Wo = (const float*)d_in[8];
    const float* bo = (const float*)d_in[9];
    float* out = (float*)d_out;

    const size_t NE = (size_t)Mm * Hh;           // 4M elems
    unsigned short* q    = (unsigned short*)d_ws;
    unsigned short* k    = q + NE;
    unsigned short* v    = k + NE;
    unsigned short* ao   = v + NE;
    unsigned short* xb   = ao + NE;
    unsigned short* wall = xb + NE;              // [Wq;Wk;Wv;Wo] rows, 4M elems
    unsigned short* wo   = wall + 3u * 1048576u;

    convert_k<<<(2 * NE) / (256 * 8), 256, 0, stream>>>(x, Wq, Wk, Wv, Wo, xb, wall);
    gemm_qkv_k<<<dim3(Mm / 128, 3072 / 128), 256, 0, stream>>>(
        xb, wall, bq, bk, bv, q, k, v);
    rope_k<<<(Mm * 128) / 256, 256, 0, stream>>>(q, k);
    flash_k<<<dim3(Ss / 128, NHh, Bb), 256, 0, stream>>>(q, k, v, am, ao);
    gemm_out_k<<<dim3(Mm / 128, Hh / 128), 256, 0, stream>>>(ao, wo, bo, out);
}

// Round 5
// 171.345 us; speedup vs baseline: 5.9104x; 1.2966x over previous
//
#include <hip/hip_runtime.h>
#include <hip/hip_bf16.h>

// GQA forward, round 4: swapped-QK^T flash attention (lane-column queries),
// ones-MFMA row sums, cvt_pk packed P, defer-max, gload_lds K, XCD remap.
// B=2, S=2048, HIDDEN=1024, 16 heads x 64 dim, RoPE over full hidden (half=512).
// ws layout (ushort elems): q(4M) k(4M) v(4M) ao(4M) xb(4M) wall(4M) = 48 MB.

constexpr int Bb  = 2;
constexpr int Ss  = 2048;
constexpr int Hh  = 1024;
constexpr int NHh = 16;
constexpr int Mm  = Bb * Ss;   // 4096 rows

typedef __attribute__((ext_vector_type(8))) unsigned short ushort8;
typedef __attribute__((ext_vector_type(4))) unsigned short ushort4_t;
typedef __attribute__((ext_vector_type(8))) short short8;
typedef __attribute__((ext_vector_type(4))) float f32x4;

__device__ __forceinline__ unsigned short f2bf(float f) {
    unsigned int u = __float_as_uint(f);
    u += 0x7fffu + ((u >> 16) & 1u);
    return (unsigned short)(u >> 16);
}
__device__ __forceinline__ float bf2f(unsigned short h) {
    return __uint_as_float(((unsigned int)h) << 16);
}
__device__ __forceinline__ void gload16(const void* g, void* l) {
    __builtin_amdgcn_global_load_lds(
        (const __attribute__((address_space(1))) unsigned int*)g,
        (__attribute__((address_space(3))) unsigned int*)l, 16, 0, 0);
}

// ---------------- fp32 -> bf16 convert (x, Wq|Wk|Wv|Wo into one block) ----------
__global__ __launch_bounds__(256) void convert_k(
    const float* __restrict__ x,
    const float* __restrict__ Wq, const float* __restrict__ Wk,
    const float* __restrict__ Wv, const float* __restrict__ Wo,
    unsigned short* __restrict__ xb, unsigned short* __restrict__ wall)
{
    size_t e = ((size_t)blockIdx.x * 256 + threadIdx.x) << 3;
    const float* s; unsigned short* d;
    if (e < (size_t)Mm * Hh) {
        s = x + e; d = xb + e;
    } else {
        size_t f = e - (size_t)Mm * Hh;
        int t = (int)(f >> 20);
        const float* w = (t == 0) ? Wq : (t == 1) ? Wk : (t == 2) ? Wv : Wo;
        s = w + (f & 1048575);
        d = wall + f;
    }
    float4 a = *(const float4*)s;
    float4 b = *(const float4*)(s + 4);
    ushort8 o;
    o[0] = f2bf(a.x); o[1] = f2bf(a.y); o[2] = f2bf(a.z); o[3] = f2bf(a.w);
    o[4] = f2bf(b.x); o[5] = f2bf(b.y); o[6] = f2bf(b.z); o[7] = f2bf(b.w);
    *(ushort8*)d = o;
}

// ---------------- bf16 MFMA GEMM core (unchanged from round 3) -------------------
#define GEMM_BODY(ATYPE_PTR, WPTR, K0MAX)                                          \
    __shared__ unsigned short As[128 * 64];                                        \
    __shared__ unsigned short Bs[128 * 64];                                        \
    const int tid  = threadIdx.x;                                                  \
    const int lane = tid & 63;                                                     \
    const int w    = tid >> 6;                                                     \
    const int wr   = w >> 1, wc = w & 1;                                           \
    const int l16  = lane & 15, g = lane >> 4;                                     \
    const int R0   = blockIdx.x * 128;                                             \
    char* asb = (char*)As; char* bsb = (char*)Bs;                                  \
    f32x4 acc[4][4] = {};                                                          \
    for (int k0 = 0; k0 < K0MAX; k0 += 64) {                                       \
        _Pragma("unroll")                                                          \
        for (int it = 0; it < 4; ++it) {                                           \
            int sbase = w * 4096 + it * 1024;                                      \
            int boff  = sbase + lane * 16;                                         \
            int r     = boff >> 7;                                                 \
            int c     = (boff >> 4) & 7;                                           \
            int col   = k0 + ((c ^ (r & 7)) << 3);                                 \
            gload16(&ATYPE_PTR[(size_t)(R0 + r) * 1024 + col], asb + sbase);       \
            gload16(&WPTR[(size_t)(gn + r) * 1024 + col], bsb + sbase);            \
        }                                                                          \
        __syncthreads();                                                           \
        short8 bfrag[4][2];                                                        \
        _Pragma("unroll")                                                          \
        for (int u = 0; u < 4; ++u) {                                              \
            int row = wc * 64 + u * 16 + l16;                                      \
            _Pragma("unroll")                                                      \
            for (int s = 0; s < 2; ++s)                                            \
                bfrag[u][s] = *(const short8*)(bsb + row * 128 +                   \
                               ((s * 64 + g * 16) ^ ((row & 7) << 4)));            \
        }                                                                          \
        _Pragma("unroll")                                                          \
        for (int t = 0; t < 4; ++t) {                                              \
            int row = wr * 64 + t * 16 + l16;                                      \
            short8 af[2];                                                          \
            _Pragma("unroll")                                                      \
            for (int s = 0; s < 2; ++s)                                            \
                af[s] = *(const short8*)(asb + row * 128 +                         \
                         ((s * 64 + g * 16) ^ ((row & 7) << 4)));                  \
            _Pragma("unroll")                                                      \
            for (int u = 0; u < 4; ++u) {                                          \
                acc[t][u] = __builtin_amdgcn_mfma_f32_16x16x32_bf16(af[0], bfrag[u][0], acc[t][u], 0, 0, 0); \
                acc[t][u] = __builtin_amdgcn_mfma_f32_16x16x32_bf16(af[1], bfrag[u][1], acc[t][u], 0, 0, 0); \
            }                                                                      \
        }                                                                          \
        __syncthreads();                                                           \
    }

__global__ __launch_bounds__(256) void gemm_qkv_k(
    const unsigned short* __restrict__ xb, const unsigned short* __restrict__ wall,
    const float* __restrict__ bq, const float* __restrict__ bk, const float* __restrict__ bv,
    unsigned short* __restrict__ q, unsigned short* __restrict__ k2,
    unsigned short* __restrict__ v)
{
    const int gn = blockIdx.y * 128;
    GEMM_BODY(xb, wall, 1024)

    const int sel = gn >> 10;
    const int n0  = gn & 1023;
    const float* bias = (sel == 0) ? bq : (sel == 1) ? bk : bv;
    unsigned short* outp = (sel == 0) ? q : (sel == 1) ? k2 : v;
    #pragma unroll
    for (int u = 0; u < 4; ++u) {
        int coll = wc * 64 + u * 16 + l16;
        float bb = bias[n0 + coll];
        #pragma unroll
        for (int t = 0; t < 4; ++t)
            #pragma unroll
            for (int rr = 0; rr < 4; ++rr) {
                int row = R0 + wr * 64 + t * 16 + g * 4 + rr;
                outp[(size_t)row * 1024 + n0 + coll] = f2bf(acc[t][u][rr] + bb);
            }
    }
}

__global__ __launch_bounds__(256) void gemm_out_k(
    const unsigned short* __restrict__ ao, const unsigned short* __restrict__ wo,
    const float* __restrict__ bo, float* __restrict__ out)
{
    const int gn = blockIdx.y * 128;
    GEMM_BODY(ao, wo, 1024)

    #pragma unroll
    for (int u = 0; u < 4; ++u) {
        int coll = wc * 64 + u * 16 + l16;
        float bb = bo[gn + coll];
        #pragma unroll
        for (int t = 0; t < 4; ++t)
            #pragma unroll
            for (int rr = 0; rr < 4; ++rr) {
                int row = R0 + wr * 64 + t * 16 + g * 4 + rr;
                out[(size_t)row * 1024 + gn + coll] = acc[t][u][rr] + bb;
            }
    }
}

// ---------------- RoPE on bf16 (unchanged) ---------------------------------------
__global__ __launch_bounds__(256) void rope_k(
    unsigned short* __restrict__ q, unsigned short* __restrict__ kk)
{
    int idx = blockIdx.x * 256 + threadIdx.x;
    int row = idx >> 7;
    int j4  = (idx & 127) << 2;
    int pos = row & (Ss - 1);
    size_t base = (size_t)row * 1024;

    ushort4_t qa = *(ushort4_t*)&q[base + j4];
    ushort4_t qb = *(ushort4_t*)&q[base + 512 + j4];
    ushort4_t ka = *(ushort4_t*)&kk[base + j4];
    ushort4_t kb = *(ushort4_t*)&kk[base + 512 + j4];

    #pragma unroll
    for (int t = 0; t < 4; ++t) {
        float jj = (float)(j4 + t);
        float inv = exp2f(jj * -0.0259525632621414f);  // 10000^(-j/512)
        float ang = (float)pos * inv;
        float sn, cs;
        __sincosf(ang, &sn, &cs);
        float a = bf2f(qa[t]), b = bf2f(qb[t]);
        qa[t] = f2bf(a * cs - b * sn);
        qb[t] = f2bf(b * cs + a * sn);
        float c = bf2f(ka[t]), d = bf2f(kb[t]);
        ka[t] = f2bf(c * cs - d * sn);
        kb[t] = f2bf(d * cs + c * sn);
    }
    *(ushort4_t*)&q[base + j4]        = qa;
    *(ushort4_t*)&q[base + 512 + j4]  = qb;
    *(ushort4_t*)&kk[base + j4]       = ka;
    *(ushort4_t*)&kk[base + 512 + j4] = kb;
}

// ---------------- Flash attention, swapped-QK^T bf16 MFMA ------------------------
// S^T = mfma(K, Q): query = lane column (l16), key = g*4+r rows. Row-max is
// in-lane + 2 shfls; row-sum via ones-MFMA in PV layout; P packed with cvt_pk.
__global__ __launch_bounds__(256) void flash_k(
    const unsigned short* __restrict__ q, const unsigned short* __restrict__ k,
    const unsigned short* __restrict__ v, const int* __restrict__ mask,
    unsigned short* __restrict__ ao)
{
    __shared__ unsigned short Ks[64 * 64];    // 8 KB, rows swizzled
    __shared__ unsigned short Vt[64 * 64];    // 8 KB, [d][key] swizzled
    __shared__ unsigned short Pb[4][32 * 64]; // 16 KB, per-wave [q][key]

    // XCD-aware remap: 16 q-blocks of one (h,bz) -> one XCD (round-robin model)
    const int F   = blockIdx.x + 16 * blockIdx.y + 256 * blockIdx.z;
    const int xcd = F & 7, j = F >> 3;
    const int grp = xcd + 8 * (j >> 4);      // 0..31
    const int qb  = j & 15;
    const int h   = grp & 15;
    const int bz  = grp >> 4;

    const int tid  = threadIdx.x;
    const int lane = tid & 63;
    const int w    = tid >> 6;
    const int l16  = lane & 15;
    const int g    = lane >> 4;       // 0..3
    const int sw   = (lane & 7) << 4; // XOR key for row-reads (row%16 == l16)

    char* ksb = (char*)&Ks[0];
    char* vtb = (char*)&Vt[0];
    char* pbb = (char*)&Pb[w][0];

    const int qrowbase = bz * Ss + qb * 128 + w * 32;

    // Q fragments: lane l16 = query col, elems d = s*32 + g*8 + e
    short8 qf[2][2];
    #pragma unroll
    for (int t = 0; t < 2; ++t)
        #pragma unroll
        for (int s = 0; s < 2; ++s)
            qf[t][s] = *(const short8*)&q[(size_t)(qrowbase + t * 16 + l16) * 1024
                                          + h * 64 + s * 32 + g * 8];

    f32x4 O[2][4];
    #pragma unroll
    for (int t = 0; t < 2; ++t)
        #pragma unroll
        for (int d = 0; d < 4; ++d) O[t][d] = (f32x4)0.f;
    f32x4 Osum[2];
    Osum[0] = (f32x4)0.f; Osum[1] = (f32x4)0.f;
    float mrow[2] = {-1e30f, -1e30f};

    const float SCALE = 0.18033688011112042f;  // (1/8) * log2(e)
    const float THR   = 10.0f;                 // defer-max threshold (log2 domain)

    short8 ones;
    #pragma unroll
    for (int e = 0; e < 8; ++e) ones[e] = (short)0x3F80;  // bf16 1.0

    for (int kt = 0; kt < Ss / 64; ++kt) {
        // ---- stage K via global_load_lds (linear dest, inverse-swizzled src) ----
        #pragma unroll
        for (int it = 0; it < 2; ++it) {
            int cid = w * 128 + it * 64 + lane;     // 16B chunk id, 0..511
            int row = cid >> 3;
            int sub = cid & 7;
            gload16(&k[(size_t)(bz * Ss + kt * 64 + row) * 1024 + h * 64
                       + ((sub ^ (row & 7)) << 3)],
                    ksb + w * 2048 + it * 1024);
        }
        // ---- stage V transposed (Vt[d][key], swizzled) ----
        {
            int kv    = tid & 63;
            int dbase = (tid >> 6) << 4;
            #pragma unroll
            for (int half = 0; half < 2; ++half) {
                int d0 = dbase + half * 8;
                ushort8 t8 = *(const ushort8*)&v[(size_t)(bz * Ss + kt * 64 + kv) * 1024
                                                 + h * 64 + d0];
                #pragma unroll
                for (int jj = 0; jj < 8; ++jj) {
                    int d = d0 + jj;
                    *(unsigned short*)(vtb + d * 128 + ((kv * 2) ^ ((d & 7) << 4))) = t8[jj];
                }
            }
        }
        __syncthreads();

        // ---- S^T = K . Q^T : row = key (g*4+r within kt4-tile), col = query ----
        f32x4 S[2][4];
        #pragma unroll
        for (int t = 0; t < 2; ++t)
            #pragma unroll
            for (int kt4 = 0; kt4 < 4; ++kt4) S[t][kt4] = (f32x4)0.f;

        #pragma unroll
        for (int kt4 = 0; kt4 < 4; ++kt4) {
            int key = kt4 * 16 + l16;
            short8 kf0 = *(const short8*)(ksb + key * 128 + ((g * 16) ^ sw));
            short8 kf1 = *(const short8*)(ksb + key * 128 + ((64 + g * 16) ^ sw));
            #pragma unroll
            for (int t = 0; t < 2; ++t) {
                S[t][kt4] = __builtin_amdgcn_mfma_f32_16x16x32_bf16(kf0, qf[t][0], S[t][kt4], 0, 0, 0);
                S[t][kt4] = __builtin_amdgcn_mfma_f32_16x16x32_bf16(kf1, qf[t][1], S[t][kt4], 0, 0, 0);
            }
        }

        // ---- mask + scale (key = kt*64 + kt4*16 + g*4 + r) ----
        int mk[4][4];
        #pragma unroll
        for (int kt4 = 0; kt4 < 4; ++kt4)
            *(int4*)&mk[kt4][0] = *(const int4*)&mask[bz * Ss + kt * 64 + kt4 * 16 + g * 4];
        #pragma unroll
        for (int t = 0; t < 2; ++t)
            #pragma unroll
            for (int kt4 = 0; kt4 < 4; ++kt4)
                #pragma unroll
                for (int r = 0; r < 4; ++r)
                    S[t][kt4][r] = mk[kt4][r] ? S[t][kt4][r] * SCALE : -1e30f;

        // ---- row max: in-lane over 16, then across g (lanes +16, +32) ----
        float rm[2];
        #pragma unroll
        for (int t = 0; t < 2; ++t) {
            float m01 = fmaxf(fmaxf(S[t][0][0], S[t][0][1]), fmaxf(S[t][0][2], S[t][0][3]));
            float m23 = fmaxf(fmaxf(S[t][1][0], S[t][1][1]), fmaxf(S[t][1][2], S[t][1][3]));
            float m45 = fmaxf(fmaxf(S[t][2][0], S[t][2][1]), fmaxf(S[t][2][2], S[t][2][3]));
            float m67 = fmaxf(fmaxf(S[t][3][0], S[t][3][1]), fmaxf(S[t][3][2], S[t][3][3]));
            float m = fmaxf(fmaxf(m01, m23), fmaxf(m45, m67));
            m = fmaxf(m, __shfl_xor(m, 16));
            m = fmaxf(m, __shfl_xor(m, 32));
            rm[t] = m;
        }

        // ---- defer-max: rescale only when max grows past THR ----
        bool grow = (rm[0] > mrow[0] + THR) || (rm[1] > mrow[1] + THR);
        if (__any((int)grow)) {
            float mn0 = fmaxf(mrow[0], rm[0]);
            float mn1 = fmaxf(mrow[1], rm[1]);
            float rs0 = exp2f(mrow[0] - mn0);
            float rs1 = exp2f(mrow[1] - mn1);
            mrow[0] = mn0; mrow[1] = mn1;
            #pragma unroll
            for (int r = 0; r < 4; ++r) {
                float f0 = __shfl(rs0, g * 4 + r);   // S-layout -> O-layout
                float f1 = __shfl(rs1, g * 4 + r);
                #pragma unroll
                for (int dt = 0; dt < 4; ++dt) { O[0][dt][r] *= f0; O[1][dt][r] *= f1; }
                Osum[0][r] *= f0; Osum[1][r] *= f1;
            }
        }

        // ---- P = exp2(S - m), pack pairs, ds_write_b64 to per-wave LDS ----
        #pragma unroll
        for (int t = 0; t < 2; ++t)
            #pragma unroll
            for (int kt4 = 0; kt4 < 4; ++kt4) {
                float p0 = exp2f(S[t][kt4][0] - mrow[t]);
                float p1 = exp2f(S[t][kt4][1] - mrow[t]);
                float p2 = exp2f(S[t][kt4][2] - mrow[t]);
                float p3 = exp2f(S[t][kt4][3] - mrow[t]);
                unsigned int u01, u23;
                asm("v_cvt_pk_bf16_f32 %0, %1, %2" : "=v"(u01) : "v"(p0), "v"(p1));
                asm("v_cvt_pk_bf16_f32 %0, %1, %2" : "=v"(u23) : "v"(p2), "v"(p3));
                int prow = t * 16 + l16;
                int pbyte = (kt4 * 32 + g * 8) ^ ((prow & 7) << 4);
                *(uint2*)(pbb + prow * 128 + pbyte) = make_uint2(u01, u23);
            }

        // ---- PV (+ ones column for row sums) ----
        #pragma unroll
        for (int ks = 0; ks < 2; ++ks) {
            short8 pf0 = *(const short8*)(pbb + l16 * 128 + ((ks * 64 + g * 16) ^ sw));
            short8 pf1 = *(const short8*)(pbb + (16 + l16) * 128 + ((ks * 64 + g * 16) ^ sw));
            Osum[0] = __builtin_amdgcn_mfma_f32_16x16x32_bf16(pf0, ones, Osum[0], 0, 0, 0);
            Osum[1] = __builtin_amdgcn_mfma_f32_16x16x32_bf16(pf1, ones, Osum[1], 0, 0, 0);
            #pragma unroll
            for (int dt = 0; dt < 4; ++dt) {
                short8 vf = *(const short8*)(vtb + (dt * 16 + l16) * 128 + ((ks * 64 + g * 16) ^ sw));
                O[0][dt] = __builtin_amdgcn_mfma_f32_16x16x32_bf16(pf0, vf, O[0][dt], 0, 0, 0);
                O[1][dt] = __builtin_amdgcn_mfma_f32_16x16x32_bf16(pf1, vf, O[1][dt], 0, 0, 0);
            }
        }
        __syncthreads();
    }

    // ---- epilogue: normalize by Osum (already in O layout), store bf16 ----
    #pragma unroll
    for (int t = 0; t < 2; ++t)
        #pragma unroll
        for (int r = 0; r < 4; ++r) {
            float inv = 1.0f / Osum[t][r];
            int row = qrowbase + t * 16 + g * 4 + r;
            #pragma unroll
            for (int dt = 0; dt < 4; ++dt)
                ao[(size_t)row * 1024 + h * 64 + dt * 16 + l16] = f2bf(O[t][dt][r] * inv);
        }
}

extern "C" void kernel_launch(void* const* d_in, const int* in_sizes, int n_in,
                              void* d_out, int out_size, void* d_ws, size_t ws_size,
                              hipStream_t stream)
{
    const float* x  = (const float*)d_in[0];
    const int*   am = (const int*)d_in[1];
    const float* Wq = (const float*)d_in[2];
    const float* bq = (const float*)d_in[3];
    const float* Wk = (const float*)d_in[4];
    const float* bk = (const float*)d_in[5];
    const float* Wv = (const float*)d_in[6];
    const float* bv = (const float*)d_in[7];
    const float* Wo = (const float*)d_in[8];
    const float* bo = (const float*)d_in[9];
    float* out = (float*)d_out;

    const size_t NE = (size_t)Mm * Hh;           // 4M elems
    unsigned short* q    = (unsigned short*)d_ws;
    unsigned short* k    = q + NE;
    unsigned short* v    = k + NE;
    unsigned short* ao   = v + NE;
    unsigned short* xb   = ao + NE;
    unsigned short* wall = xb + NE;              // [Wq;Wk;Wv;Wo] rows
    unsigned short* wo   = wall + 3u * 1048576u;

    convert_k<<<(2 * NE) / (256 * 8), 256, 0, stream>>>(x, Wq, Wk, Wv, Wo, xb, wall);
    gemm_qkv_k<<<dim3(Mm / 128, 3072 / 128), 256, 0, stream>>>(
        xb, wall, bq, bk, bv, q, k, v);
    rope_k<<<(Mm * 128) / 256, 256, 0, stream>>>(q, k);
    flash_k<<<dim3(Ss / 128, NHh, Bb), 256, 0, stream>>>(q, k, v, am, ao);
    gemm_out_k<<<dim3(Mm / 128, Hh / 128), 256, 0, stream>>>(ao, wo, bo, out);
}

// Round 6
// 168.169 us; speedup vs baseline: 6.0221x; 1.0189x over previous
//
#include <hip/hip_runtime.h>
#include <hip/hip_bf16.h>

// GQA forward, round 5: flash attention with 64-query blocks (4 blocks/CU),
// pre-scaled Q (no per-element scale mul), swapped QK^T, ones-MFMA row sums,
// cvt_pk packed P, defer-max, gload_lds K staging, bijective XCD remap.
// B=2, S=2048, HIDDEN=1024, 16 heads x 64 dim, RoPE over full hidden (half=512).
// ws layout (ushort elems): q(4M) k(4M) v(4M) ao(4M) xb(4M) wall(4M) = 48 MB.

constexpr int Bb  = 2;
constexpr int Ss  = 2048;
constexpr int Hh  = 1024;
constexpr int NHh = 16;
constexpr int Mm  = Bb * Ss;   // 4096 rows

typedef __attribute__((ext_vector_type(8))) unsigned short ushort8;
typedef __attribute__((ext_vector_type(4))) unsigned short ushort4_t;
typedef __attribute__((ext_vector_type(8))) short short8;
typedef __attribute__((ext_vector_type(4))) float f32x4;

__device__ __forceinline__ unsigned short f2bf(float f) {
    unsigned int u = __float_as_uint(f);
    u += 0x7fffu + ((u >> 16) & 1u);
    return (unsigned short)(u >> 16);
}
__device__ __forceinline__ float bf2f(unsigned short h) {
    return __uint_as_float(((unsigned int)h) << 16);
}
__device__ __forceinline__ void gload16(const void* g, void* l) {
    __builtin_amdgcn_global_load_lds(
        (const __attribute__((address_space(1))) unsigned int*)g,
        (__attribute__((address_space(3))) unsigned int*)l, 16, 0, 0);
}

// ---------------- fp32 -> bf16 convert (x, Wq|Wk|Wv|Wo into one block) ----------
__global__ __launch_bounds__(256) void convert_k(
    const float* __restrict__ x,
    const float* __restrict__ Wq, const float* __restrict__ Wk,
    const float* __restrict__ Wv, const float* __restrict__ Wo,
    unsigned short* __restrict__ xb, unsigned short* __restrict__ wall)
{
    size_t e = ((size_t)blockIdx.x * 256 + threadIdx.x) << 3;
    const float* s; unsigned short* d;
    if (e < (size_t)Mm * Hh) {
        s = x + e; d = xb + e;
    } else {
        size_t f = e - (size_t)Mm * Hh;
        int t = (int)(f >> 20);
        const float* w = (t == 0) ? Wq : (t == 1) ? Wk : (t == 2) ? Wv : Wo;
        s = w + (f & 1048575);
        d = wall + f;
    }
    float4 a = *(const float4*)s;
    float4 b = *(const float4*)(s + 4);
    ushort8 o;
    o[0] = f2bf(a.x); o[1] = f2bf(a.y); o[2] = f2bf(a.z); o[3] = f2bf(a.w);
    o[4] = f2bf(b.x); o[5] = f2bf(b.y); o[6] = f2bf(b.z); o[7] = f2bf(b.w);
    *(ushort8*)d = o;
}

// ---------------- bf16 MFMA GEMM core ---------------------------------------------
#define GEMM_BODY(ATYPE_PTR, WPTR, K0MAX)                                          \
    __shared__ unsigned short As[128 * 64];                                        \
    __shared__ unsigned short Bs[128 * 64];                                        \
    const int tid  = threadIdx.x;                                                  \
    const int lane = tid & 63;                                                     \
    const int w    = tid >> 6;                                                     \
    const int wr   = w >> 1, wc = w & 1;                                           \
    const int l16  = lane & 15, g = lane >> 4;                                     \
    const int R0   = blockIdx.x * 128;                                             \
    char* asb = (char*)As; char* bsb = (char*)Bs;                                  \
    f32x4 acc[4][4] = {};                                                          \
    for (int k0 = 0; k0 < K0MAX; k0 += 64) {                                       \
        _Pragma("unroll")                                                          \
        for (int it = 0; it < 4; ++it) {                                           \
            int sbase = w * 4096 + it * 1024;                                      \
            int boff  = sbase + lane * 16;                                         \
            int r     = boff >> 7;                                                 \
            int c     = (boff >> 4) & 7;                                           \
            int col   = k0 + ((c ^ (r & 7)) << 3);                                 \
            gload16(&ATYPE_PTR[(size_t)(R0 + r) * 1024 + col], asb + sbase);       \
            gload16(&WPTR[(size_t)(gn + r) * 1024 + col], bsb + sbase);            \
        }                                                                          \
        __syncthreads();                                                           \
        short8 bfrag[4][2];                                                        \
        _Pragma("unroll")                                                          \
        for (int u = 0; u < 4; ++u) {                                              \
            int row = wc * 64 + u * 16 + l16;                                      \
            _Pragma("unroll")                                                      \
            for (int s = 0; s < 2; ++s)                                            \
                bfrag[u][s] = *(const short8*)(bsb + row * 128 +                   \
                               ((s * 64 + g * 16) ^ ((row & 7) << 4)));            \
        }                                                                          \
        _Pragma("unroll")                                                          \
        for (int t = 0; t < 4; ++t) {                                              \
            int row = wr * 64 + t * 16 + l16;                                      \
            short8 af[2];                                                          \
            _Pragma("unroll")                                                      \
            for (int s = 0; s < 2; ++s)                                            \
                af[s] = *(const short8*)(asb + row * 128 +                         \
                         ((s * 64 + g * 16) ^ ((row & 7) << 4)));                  \
            _Pragma("unroll")                                                      \
            for (int u = 0; u < 4; ++u) {                                          \
                acc[t][u] = __builtin_amdgcn_mfma_f32_16x16x32_bf16(af[0], bfrag[u][0], acc[t][u], 0, 0, 0); \
                acc[t][u] = __builtin_amdgcn_mfma_f32_16x16x32_bf16(af[1], bfrag[u][1], acc[t][u], 0, 0, 0); \
            }                                                                      \
        }                                                                          \
        __syncthreads();                                                           \
    }

__global__ __launch_bounds__(256) void gemm_qkv_k(
    const unsigned short* __restrict__ xb, const unsigned short* __restrict__ wall,
    const float* __restrict__ bq, const float* __restrict__ bk, const float* __restrict__ bv,
    unsigned short* __restrict__ q, unsigned short* __restrict__ k2,
    unsigned short* __restrict__ v)
{
    const int gn = blockIdx.y * 128;
    GEMM_BODY(xb, wall, 1024)

    const int sel = gn >> 10;
    const int n0  = gn & 1023;
    const float* bias = (sel == 0) ? bq : (sel == 1) ? bk : bv;
    unsigned short* outp = (sel == 0) ? q : (sel == 1) ? k2 : v;
    // Pre-scale q by (1/8)*log2e: q feeds only QK^T; scale commutes with RoPE.
    const float qs = (sel == 0) ? 0.18033688011112042f : 1.0f;
    #pragma unroll
    for (int u = 0; u < 4; ++u) {
        int coll = wc * 64 + u * 16 + l16;
        float bb = bias[n0 + coll];
        #pragma unroll
        for (int t = 0; t < 4; ++t)
            #pragma unroll
            for (int rr = 0; rr < 4; ++rr) {
                int row = R0 + wr * 64 + t * 16 + g * 4 + rr;
                outp[(size_t)row * 1024 + n0 + coll] = f2bf((acc[t][u][rr] + bb) * qs);
            }
    }
}

__global__ __launch_bounds__(256) void gemm_out_k(
    const unsigned short* __restrict__ ao, const unsigned short* __restrict__ wo,
    const float* __restrict__ bo, float* __restrict__ out)
{
    const int gn = blockIdx.y * 128;
    GEMM_BODY(ao, wo, 1024)

    #pragma unroll
    for (int u = 0; u < 4; ++u) {
        int coll = wc * 64 + u * 16 + l16;
        float bb = bo[gn + coll];
        #pragma unroll
        for (int t = 0; t < 4; ++t)
            #pragma unroll
            for (int rr = 0; rr < 4; ++rr) {
                int row = R0 + wr * 64 + t * 16 + g * 4 + rr;
                out[(size_t)row * 1024 + gn + coll] = acc[t][u][rr] + bb;
            }
    }
}

// ---------------- RoPE on bf16 ----------------------------------------------------
__global__ __launch_bounds__(256) void rope_k(
    unsigned short* __restrict__ q, unsigned short* __restrict__ kk)
{
    int idx = blockIdx.x * 256 + threadIdx.x;
    int row = idx >> 7;
    int j4  = (idx & 127) << 2;
    int pos = row & (Ss - 1);
    size_t base = (size_t)row * 1024;

    ushort4_t qa = *(ushort4_t*)&q[base + j4];
    ushort4_t qb = *(ushort4_t*)&q[base + 512 + j4];
    ushort4_t ka = *(ushort4_t*)&kk[base + j4];
    ushort4_t kb = *(ushort4_t*)&kk[base + 512 + j4];

    #pragma unroll
    for (int t = 0; t < 4; ++t) {
        float jj = (float)(j4 + t);
        float inv = exp2f(jj * -0.0259525632621414f);  // 10000^(-j/512)
        float ang = (float)pos * inv;
        float sn, cs;
        __sincosf(ang, &sn, &cs);
        float a = bf2f(qa[t]), b = bf2f(qb[t]);
        qa[t] = f2bf(a * cs - b * sn);
        qb[t] = f2bf(b * cs + a * sn);
        float c = bf2f(ka[t]), d = bf2f(kb[t]);
        ka[t] = f2bf(c * cs - d * sn);
        kb[t] = f2bf(d * cs + c * sn);
    }
    *(ushort4_t*)&q[base + j4]        = qa;
    *(ushort4_t*)&q[base + 512 + j4]  = qb;
    *(ushort4_t*)&kk[base + j4]       = ka;
    *(ushort4_t*)&kk[base + 512 + j4] = kb;
}

// ---------------- Flash attention: 64-query blocks, 16 q/wave --------------------
__global__ __launch_bounds__(256, 4) void flash_k(
    const unsigned short* __restrict__ q, const unsigned short* __restrict__ k,
    const unsigned short* __restrict__ v, const int* __restrict__ mask,
    unsigned short* __restrict__ ao)
{
    __shared__ unsigned short Ks[64 * 64];    // 8 KB, rows swizzled
    __shared__ unsigned short Vt[64 * 64];    // 8 KB, [d][key] swizzled
    __shared__ unsigned short Pb[4][16 * 64]; // 8 KB, per-wave [q][key]

    // Bijective XCD remap: 1024 blocks, 128/XCD = 4 (h,bz) groups x 32 q-blocks.
    const int F   = blockIdx.x;
    const int xcd = F & 7, j = F >> 3;
    const int grp = xcd * 4 + (j >> 5);      // 0..31
    const int qb  = j & 31;
    const int h   = grp & 15;
    const int bz  = grp >> 4;

    const int tid  = threadIdx.x;
    const int lane = tid & 63;
    const int w    = tid >> 6;
    const int l16  = lane & 15;
    const int g    = lane >> 4;       // 0..3
    const int sw   = (lane & 7) << 4; // XOR key for rows with row&7 == lane&7

    char* ksb = (char*)&Ks[0];
    char* vtb = (char*)&Vt[0];
    char* pbb = (char*)&Pb[w][0];

    const int qrowbase = bz * Ss + qb * 64 + w * 16;

    // Q fragments (pre-scaled by (1/8)*log2e): lane l16 = query, elems s*32+g*8
    short8 qf[2];
    #pragma unroll
    for (int s = 0; s < 2; ++s)
        qf[s] = *(const short8*)&q[(size_t)(qrowbase + l16) * 1024
                                   + h * 64 + s * 32 + g * 8];

    f32x4 O[4];
    #pragma unroll
    for (int d = 0; d < 4; ++d) O[d] = (f32x4)0.f;
    f32x4 Osum = (f32x4)0.f;
    float mrow = -1.0e4f;   // low enough to rescale on first live tile; keeps
                            // exp2(-1e30 - mrow) == 0 for all-masked tiles

    const float THR = 10.0f;  // defer-max threshold (log2 domain)

    short8 ones;
    #pragma unroll
    for (int e = 0; e < 8; ++e) ones[e] = (short)0x3F80;  // bf16 1.0

    for (int kt = 0; kt < Ss / 64; ++kt) {
        // ---- stage K via global_load_lds (linear dest, inverse-swizzled src) ----
        #pragma unroll
        for (int it = 0; it < 2; ++it) {
            int cid = w * 128 + it * 64 + lane;     // 16B chunk id, 0..511
            int row = cid >> 3;
            int sub = cid & 7;
            gload16(&k[(size_t)(bz * Ss + kt * 64 + row) * 1024 + h * 64
                       + ((sub ^ (row & 7)) << 3)],
                    ksb + w * 2048 + it * 1024);
        }
        // ---- stage V transposed (Vt[d][key], swizzled) ----
        {
            int kv    = tid & 63;
            int dbase = (tid >> 6) << 4;
            #pragma unroll
            for (int half = 0; half < 2; ++half) {
                int d0 = dbase + half * 8;
                ushort8 t8 = *(const ushort8*)&v[(size_t)(bz * Ss + kt * 64 + kv) * 1024
                                                 + h * 64 + d0];
                #pragma unroll
                for (int jj = 0; jj < 8; ++jj) {
                    int d = d0 + jj;
                    *(unsigned short*)(vtb + d * 128 + ((kv * 2) ^ ((d & 7) << 4))) = t8[jj];
                }
            }
        }
        __syncthreads();

        // ---- S^T = K . Q^T : row = key (g*4+r), col = query (l16) ----
        f32x4 S[4];
        #pragma unroll
        for (int kt4 = 0; kt4 < 4; ++kt4) S[kt4] = (f32x4)0.f;
        #pragma unroll
        for (int kt4 = 0; kt4 < 4; ++kt4) {
            int key = kt4 * 16 + l16;
            short8 kf0 = *(const short8*)(ksb + key * 128 + ((g * 16) ^ sw));
            short8 kf1 = *(const short8*)(ksb + key * 128 + ((64 + g * 16) ^ sw));
            S[kt4] = __builtin_amdgcn_mfma_f32_16x16x32_bf16(kf0, qf[0], S[kt4], 0, 0, 0);
            S[kt4] = __builtin_amdgcn_mfma_f32_16x16x32_bf16(kf1, qf[1], S[kt4], 0, 0, 0);
        }

        // ---- mask (scores already in log2 domain via pre-scaled Q) ----
        int mk[4][4];
        #pragma unroll
        for (int kt4 = 0; kt4 < 4; ++kt4)
            *(int4*)&mk[kt4][0] = *(const int4*)&mask[bz * Ss + kt * 64 + kt4 * 16 + g * 4];
        #pragma unroll
        for (int kt4 = 0; kt4 < 4; ++kt4)
            #pragma unroll
            for (int r = 0; r < 4; ++r)
                S[kt4][r] = mk[kt4][r] ? S[kt4][r] : -1e30f;

        // ---- row max: in-lane (max3-fusable nesting), then across g ----
        float m0 = fmaxf(fmaxf(S[0][0], S[0][1]), fmaxf(S[0][2], S[0][3]));
        float m1 = fmaxf(fmaxf(S[1][0], S[1][1]), fmaxf(S[1][2], S[1][3]));
        float m2 = fmaxf(fmaxf(S[2][0], S[2][1]), fmaxf(S[2][2], S[2][3]));
        float m3 = fmaxf(fmaxf(S[3][0], S[3][1]), fmaxf(S[3][2], S[3][3]));
        float m  = fmaxf(fmaxf(m0, m1), fmaxf(m2, m3));
        m = fmaxf(m, __shfl_xor(m, 16));
        m = fmaxf(m, __shfl_xor(m, 32));

        // ---- defer-max rescale ----
        if (__any((int)(m > mrow + THR))) {
            float mn = fmaxf(mrow, m);
            float rs = exp2f(mrow - mn);
            mrow = mn;
            #pragma unroll
            for (int r = 0; r < 4; ++r) {
                float f0 = __shfl(rs, g * 4 + r);   // S-layout -> O-layout
                #pragma unroll
                for (int dt = 0; dt < 4; ++dt) O[dt][r] *= f0;
                Osum[r] *= f0;
            }
        }

        // ---- P = exp2(S - m), pack pairs, b64 write to per-wave LDS ----
        #pragma unroll
        for (int kt4 = 0; kt4 < 4; ++kt4) {
            float p0 = exp2f(S[kt4][0] - mrow);
            float p1 = exp2f(S[kt4][1] - mrow);
            float p2 = exp2f(S[kt4][2] - mrow);
            float p3 = exp2f(S[kt4][3] - mrow);
            unsigned int u01, u23;
            asm("v_cvt_pk_bf16_f32 %0, %1, %2" : "=v"(u01) : "v"(p0), "v"(p1));
            asm("v_cvt_pk_bf16_f32 %0, %1, %2" : "=v"(u23) : "v"(p2), "v"(p3));
            int pbyte = (kt4 * 32 + g * 8) ^ ((l16 & 7) << 4);
            *(uint2*)(pbb + l16 * 128 + pbyte) = make_uint2(u01, u23);
        }

        // ---- PV (+ ones column for row sums) ----
        #pragma unroll
        for (int ks = 0; ks < 2; ++ks) {
            short8 pf = *(const short8*)(pbb + l16 * 128 + ((ks * 64 + g * 16) ^ sw));
            Osum = __builtin_amdgcn_mfma_f32_16x16x32_bf16(pf, ones, Osum, 0, 0, 0);
            #pragma unroll
            for (int dt = 0; dt < 4; ++dt) {
                short8 vf = *(const short8*)(vtb + (dt * 16 + l16) * 128 + ((ks * 64 + g * 16) ^ sw));
                O[dt] = __builtin_amdgcn_mfma_f32_16x16x32_bf16(pf, vf, O[dt], 0, 0, 0);
            }
        }
        __syncthreads();
    }

    // ---- epilogue: normalize by Osum (already in O layout), store bf16 ----
    #pragma unroll
    for (int r = 0; r < 4; ++r) {
        float inv = 1.0f / Osum[r];
        int row = qrowbase + g * 4 + r;
        #pragma unroll
        for (int dt = 0; dt < 4; ++dt)
            ao[(size_t)row * 1024 + h * 64 + dt * 16 + l16] = f2bf(O[dt][r] * inv);
    }
}

extern "C" void kernel_launch(void* const* d_in, const int* in_sizes, int n_in,
                              void* d_out, int out_size, void* d_ws, size_t ws_size,
                              hipStream_t stream)
{
    const float* x  = (const float*)d_in[0];
    const int*   am = (const int*)d_in[1];
    const float* Wq = (const float*)d_in[2];
    const float* bq = (const float*)d_in[3];
    const float* Wk = (const float*)d_in[4];
    const float* bk = (const float*)d_in[5];
    const float* Wv = (const float*)d_in[6];
    const float* bv = (const float*)d_in[7];
    const float* Wo = (const float*)d_in[8];
    const float* bo = (const float*)d_in[9];
    float* out = (float*)d_out;

    const size_t NE = (size_t)Mm * Hh;           // 4M elems
    unsigned short* q    = (unsigned short*)d_ws;
    unsigned short* k    = q + NE;
    unsigned short* v    = k + NE;
    unsigned short* ao   = v + NE;
    unsigned short* xb   = ao + NE;
    unsigned short* wall = xb + NE;              // [Wq;Wk;Wv;Wo] rows
    unsigned short* wo   = wall + 3u * 1048576u;

    convert_k<<<(2 * NE) / (256 * 8), 256, 0, stream>>>(x, Wq, Wk, Wv, Wo, xb, wall);
    gemm_qkv_k<<<dim3(Mm / 128, 3072 / 128), 256, 0, stream>>>(
        xb, wall, bq, bk, bv, q, k, v);
    rope_k<<<(Mm * 128) / 256, 256, 0, stream>>>(q, k);
    flash_k<<<dim3(Ss / 64 * NHh * Bb), 256, 0, stream>>>(q, k, v, am, ao);
    gemm_out_k<<<dim3(Mm / 128, Hh / 128), 256, 0, stream>>>(ao, wo, bo, out);
}

// Round 7
// 164.418 us; speedup vs baseline: 6.1595x; 1.0228x over previous
//
#include <hip/hip_runtime.h>
#include <hip/hip_bf16.h>

// GQA forward, round 6: flash attention with 128-query blocks (32 q/wave,
// K/V fragments shared across the wave's 2 q-tiles), double-buffered K/V
// staging with prefetch (1 barrier/iter), padded Vt (no XOR VALU).
// B=2, S=2048, HIDDEN=1024, 16 heads x 64 dim, RoPE over full hidden (half=512).
// ws layout (ushort elems): q(4M) k(4M) v(4M) ao(4M) xb(4M) wall(4M) = 48 MB.

constexpr int Bb  = 2;
constexpr int Ss  = 2048;
constexpr int Hh  = 1024;
constexpr int NHh = 16;
constexpr int Mm  = Bb * Ss;   // 4096 rows

typedef __attribute__((ext_vector_type(8))) unsigned short ushort8;
typedef __attribute__((ext_vector_type(4))) unsigned short ushort4_t;
typedef __attribute__((ext_vector_type(8))) short short8;
typedef __attribute__((ext_vector_type(4))) float f32x4;

__device__ __forceinline__ unsigned short f2bf(float f) {
    unsigned int u = __float_as_uint(f);
    u += 0x7fffu + ((u >> 16) & 1u);
    return (unsigned short)(u >> 16);
}
__device__ __forceinline__ float bf2f(unsigned short h) {
    return __uint_as_float(((unsigned int)h) << 16);
}
__device__ __forceinline__ void gload16(const void* g, void* l) {
    __builtin_amdgcn_global_load_lds(
        (const __attribute__((address_space(1))) unsigned int*)g,
        (__attribute__((address_space(3))) unsigned int*)l, 16, 0, 0);
}

// ---------------- fp32 -> bf16 convert (x, Wq|Wk|Wv|Wo into one block) ----------
__global__ __launch_bounds__(256) void convert_k(
    const float* __restrict__ x,
    const float* __restrict__ Wq, const float* __restrict__ Wk,
    const float* __restrict__ Wv, const float* __restrict__ Wo,
    unsigned short* __restrict__ xb, unsigned short* __restrict__ wall)
{
    size_t e = ((size_t)blockIdx.x * 256 + threadIdx.x) << 3;
    const float* s; unsigned short* d;
    if (e < (size_t)Mm * Hh) {
        s = x + e; d = xb + e;
    } else {
        size_t f = e - (size_t)Mm * Hh;
        int t = (int)(f >> 20);
        const float* w = (t == 0) ? Wq : (t == 1) ? Wk : (t == 2) ? Wv : Wo;
        s = w + (f & 1048575);
        d = wall + f;
    }
    float4 a = *(const float4*)s;
    float4 b = *(const float4*)(s + 4);
    ushort8 o;
    o[0] = f2bf(a.x); o[1] = f2bf(a.y); o[2] = f2bf(a.z); o[3] = f2bf(a.w);
    o[4] = f2bf(b.x); o[5] = f2bf(b.y); o[6] = f2bf(b.z); o[7] = f2bf(b.w);
    *(ushort8*)d = o;
}

// ---------------- bf16 MFMA GEMM core ---------------------------------------------
#define GEMM_BODY(ATYPE_PTR, WPTR, K0MAX)                                          \
    __shared__ unsigned short As[128 * 64];                                        \
    __shared__ unsigned short Bs[128 * 64];                                        \
    const int tid  = threadIdx.x;                                                  \
    const int lane = tid & 63;                                                     \
    const int w    = tid >> 6;                                                     \
    const int wr   = w >> 1, wc = w & 1;                                           \
    const int l16  = lane & 15, g = lane >> 4;                                     \
    const int R0   = blockIdx.x * 128;                                             \
    char* asb = (char*)As; char* bsb = (char*)Bs;                                  \
    f32x4 acc[4][4] = {};                                                          \
    for (int k0 = 0; k0 < K0MAX; k0 += 64) {                                       \
        _Pragma("unroll")                                                          \
        for (int it = 0; it < 4; ++it) {                                           \
            int sbase = w * 4096 + it * 1024;                                      \
            int boff  = sbase + lane * 16;                                         \
            int r     = boff >> 7;                                                 \
            int c     = (boff >> 4) & 7;                                           \
            int col   = k0 + ((c ^ (r & 7)) << 3);                                 \
            gload16(&ATYPE_PTR[(size_t)(R0 + r) * 1024 + col], asb + sbase);       \
            gload16(&WPTR[(size_t)(gn + r) * 1024 + col], bsb + sbase);            \
        }                                                                          \
        __syncthreads();                                                           \
        short8 bfrag[4][2];                                                        \
        _Pragma("unroll")                                                          \
        for (int u = 0; u < 4; ++u) {                                              \
            int row = wc * 64 + u * 16 + l16;                                      \
            _Pragma("unroll")                                                      \
            for (int s = 0; s < 2; ++s)                                            \
                bfrag[u][s] = *(const short8*)(bsb + row * 128 +                   \
                               ((s * 64 + g * 16) ^ ((row & 7) << 4)));            \
        }                                                                          \
        _Pragma("unroll")                                                          \
        for (int t = 0; t < 4; ++t) {                                              \
            int row = wr * 64 + t * 16 + l16;                                      \
            short8 af[2];                                                          \
            _Pragma("unroll")                                                      \
            for (int s = 0; s < 2; ++s)                                            \
                af[s] = *(const short8*)(asb + row * 128 +                         \
                         ((s * 64 + g * 16) ^ ((row & 7) << 4)));                  \
            _Pragma("unroll")                                                      \
            for (int u = 0; u < 4; ++u) {                                          \
                acc[t][u] = __builtin_amdgcn_mfma_f32_16x16x32_bf16(af[0], bfrag[u][0], acc[t][u], 0, 0, 0); \
                acc[t][u] = __builtin_amdgcn_mfma_f32_16x16x32_bf16(af[1], bfrag[u][1], acc[t][u], 0, 0, 0); \
            }                                                                      \
        }                                                                          \
        __syncthreads();                                                           \
    }

__global__ __launch_bounds__(256) void gemm_qkv_k(
    const unsigned short* __restrict__ xb, const unsigned short* __restrict__ wall,
    const float* __restrict__ bq, const float* __restrict__ bk, const float* __restrict__ bv,
    unsigned short* __restrict__ q, unsigned short* __restrict__ k2,
    unsigned short* __restrict__ v)
{
    const int gn = blockIdx.y * 128;
    GEMM_BODY(xb, wall, 1024)

    const int sel = gn >> 10;
    const int n0  = gn & 1023;
    const float* bias = (sel == 0) ? bq : (sel == 1) ? bk : bv;
    unsigned short* outp = (sel == 0) ? q : (sel == 1) ? k2 : v;
    // Pre-scale q by (1/8)*log2e: q feeds only QK^T; scale commutes with RoPE.
    const float qs = (sel == 0) ? 0.18033688011112042f : 1.0f;
    #pragma unroll
    for (int u = 0; u < 4; ++u) {
        int coll = wc * 64 + u * 16 + l16;
        float bb = bias[n0 + coll];
        #pragma unroll
        for (int t = 0; t < 4; ++t)
            #pragma unroll
            for (int rr = 0; rr < 4; ++rr) {
                int row = R0 + wr * 64 + t * 16 + g * 4 + rr;
                outp[(size_t)row * 1024 + n0 + coll] = f2bf((acc[t][u][rr] + bb) * qs);
            }
    }
}

__global__ __launch_bounds__(256) void gemm_out_k(
    const unsigned short* __restrict__ ao, const unsigned short* __restrict__ wo,
    const float* __restrict__ bo, float* __restrict__ out)
{
    const int gn = blockIdx.y * 128;
    GEMM_BODY(ao, wo, 1024)

    #pragma unroll
    for (int u = 0; u < 4; ++u) {
        int coll = wc * 64 + u * 16 + l16;
        float bb = bo[gn + coll];
        #pragma unroll
        for (int t = 0; t < 4; ++t)
            #pragma unroll
            for (int rr = 0; rr < 4; ++rr) {
                int row = R0 + wr * 64 + t * 16 + g * 4 + rr;
                out[(size_t)row * 1024 + gn + coll] = acc[t][u][rr] + bb;
            }
    }
}

// ---------------- RoPE on bf16 ----------------------------------------------------
__global__ __launch_bounds__(256) void rope_k(
    unsigned short* __restrict__ q, unsigned short* __restrict__ kk)
{
    int idx = blockIdx.x * 256 + threadIdx.x;
    int row = idx >> 7;
    int j4  = (idx & 127) << 2;
    int pos = row & (Ss - 1);
    size_t base = (size_t)row * 1024;

    ushort4_t qa = *(ushort4_t*)&q[base + j4];
    ushort4_t qb = *(ushort4_t*)&q[base + 512 + j4];
    ushort4_t ka = *(ushort4_t*)&kk[base + j4];
    ushort4_t kb = *(ushort4_t*)&kk[base + 512 + j4];

    #pragma unroll
    for (int t = 0; t < 4; ++t) {
        float jj = (float)(j4 + t);
        float inv = exp2f(jj * -0.0259525632621414f);  // 10000^(-j/512)
        float ang = (float)pos * inv;
        float sn, cs;
        __sincosf(ang, &sn, &cs);
        float a = bf2f(qa[t]), b = bf2f(qb[t]);
        qa[t] = f2bf(a * cs - b * sn);
        qb[t] = f2bf(b * cs + a * sn);
        float c = bf2f(ka[t]), d = bf2f(kb[t]);
        ka[t] = f2bf(c * cs - d * sn);
        kb[t] = f2bf(d * cs + c * sn);
    }
    *(ushort4_t*)&q[base + j4]        = qa;
    *(ushort4_t*)&q[base + 512 + j4]  = qb;
    *(ushort4_t*)&kk[base + j4]       = ka;
    *(ushort4_t*)&kk[base + 512 + j4] = kb;
}

// ---------------- Flash attention: 128-q blocks, 32 q/wave, dbuf K/V -------------
__global__ __launch_bounds__(256, 3) void flash_k(
    const unsigned short* __restrict__ q, const unsigned short* __restrict__ k,
    const unsigned short* __restrict__ v, const int* __restrict__ mask,
    unsigned short* __restrict__ ao)
{
    __shared__ unsigned short Ks[2][64 * 64];   // 16 KB, XOR-swizzled rows
    __shared__ unsigned short Vt[2][64 * 72];   // 18 KB, [d][key] padded (+8)
    __shared__ unsigned short Pb[4][32 * 64];   // 16 KB, per-wave [q][key]

    // Bijective XCD remap: 512 blocks = 8 XCDs x (4 (h,bz) groups x 16 q-blocks).
    const int F   = blockIdx.x;
    const int xcd = F & 7, j = F >> 3;           // j: 0..63
    const int grp = xcd * 4 + (j >> 4);          // 0..31
    const int qb  = j & 15;
    const int h   = grp & 15;
    const int bz  = grp >> 4;

    const int tid  = threadIdx.x;
    const int lane = tid & 63;
    const int w    = tid >> 6;
    const int l16  = lane & 15;
    const int g    = lane >> 4;       // 0..3
    const int sw   = (lane & 7) << 4; // XOR key for rows with row&7 == lane&7

    const int qrowbase = bz * Ss + qb * 128 + w * 32;
    const size_t kvbase = (size_t)(bz * Ss) * 1024 + h * 64;

    // Q fragments (pre-scaled by (1/8)*log2e): [t][s], lane l16 = query
    short8 qf[2][2];
    #pragma unroll
    for (int t = 0; t < 2; ++t)
        #pragma unroll
        for (int s = 0; s < 2; ++s)
            qf[t][s] = *(const short8*)&q[(size_t)(qrowbase + t * 16 + l16) * 1024
                                          + h * 64 + s * 32 + g * 8];

    f32x4 O[2][4];
    #pragma unroll
    for (int t = 0; t < 2; ++t)
        #pragma unroll
        for (int d = 0; d < 4; ++d) O[t][d] = (f32x4)0.f;
    f32x4 Osum[2];
    Osum[0] = (f32x4)0.f; Osum[1] = (f32x4)0.f;
    float mrow[2] = {-1.0e4f, -1.0e4f};

    const float THR = 10.0f;  // defer-max threshold (log2 domain)

    short8 ones;
    #pragma unroll
    for (int e = 0; e < 8; ++e) ones[e] = (short)0x3F80;  // bf16 1.0

    // V staging geometry: thread holds key kv=lane, d = w*16 + half*8 .. +8
    const int kv    = lane;
    const int dbase = w * 16;

    // ---- prologue: stage tile 0 ----
    ushort8 vr0 = *(const ushort8*)&v[kvbase + (size_t)kv * 1024 + dbase];
    ushort8 vr1 = *(const ushort8*)&v[kvbase + (size_t)kv * 1024 + dbase + 8];
    #pragma unroll
    for (int it = 0; it < 2; ++it) {
        int cid = w * 128 + it * 64 + lane;
        int row = cid >> 3;
        int sub = cid & 7;
        gload16(&k[kvbase + (size_t)row * 1024 + ((sub ^ (row & 7)) << 3)],
                (char*)&Ks[0][0] + w * 2048 + it * 1024);
    }
    #pragma unroll
    for (int jj = 0; jj < 8; ++jj) {
        Vt[0][(dbase + jj) * 72 + kv]     = vr0[jj];
        Vt[0][(dbase + 8 + jj) * 72 + kv] = vr1[jj];
    }
    __syncthreads();

    for (int kt = 0; kt < Ss / 64; ++kt) {
        const int cur = kt & 1;
        char* ksb = (char*)&Ks[cur][0];
        char* vtb = (char*)&Vt[cur][0];
        char* pbb = (char*)&Pb[w][0];
        const bool pre = (kt + 1 < Ss / 64);

        // ---- prefetch tile kt+1: V->regs, K->LDS DMA ----
        if (pre) {
            size_t nb = kvbase + (size_t)(kt + 1) * 64 * 1024;
            vr0 = *(const ushort8*)&v[nb + (size_t)kv * 1024 + dbase];
            vr1 = *(const ushort8*)&v[nb + (size_t)kv * 1024 + dbase + 8];
            #pragma unroll
            for (int it = 0; it < 2; ++it) {
                int cid = w * 128 + it * 64 + lane;
                int row = cid >> 3;
                int sub = cid & 7;
                gload16(&k[nb + (size_t)row * 1024 + ((sub ^ (row & 7)) << 3)],
                        (char*)&Ks[cur ^ 1][0] + w * 2048 + it * 1024);
            }
        }

        // ---- S^T = K . Q^T : row = key (g*4+r), col = query (l16) ----
        f32x4 S[2][4];
        #pragma unroll
        for (int t = 0; t < 2; ++t)
            #pragma unroll
            for (int kt4 = 0; kt4 < 4; ++kt4) S[t][kt4] = (f32x4)0.f;
        #pragma unroll
        for (int kt4 = 0; kt4 < 4; ++kt4) {
            int key = kt4 * 16 + l16;
            short8 kf0 = *(const short8*)(ksb + key * 128 + ((g * 16) ^ sw));
            short8 kf1 = *(const short8*)(ksb + key * 128 + ((64 + g * 16) ^ sw));
            #pragma unroll
            for (int t = 0; t < 2; ++t) {
                S[t][kt4] = __builtin_amdgcn_mfma_f32_16x16x32_bf16(kf0, qf[t][0], S[t][kt4], 0, 0, 0);
                S[t][kt4] = __builtin_amdgcn_mfma_f32_16x16x32_bf16(kf1, qf[t][1], S[t][kt4], 0, 0, 0);
            }
        }

        // ---- mask ----
        int mk[4][4];
        #pragma unroll
        for (int kt4 = 0; kt4 < 4; ++kt4)
            *(int4*)&mk[kt4][0] = *(const int4*)&mask[bz * Ss + kt * 64 + kt4 * 16 + g * 4];
        #pragma unroll
        for (int t = 0; t < 2; ++t)
            #pragma unroll
            for (int kt4 = 0; kt4 < 4; ++kt4)
                #pragma unroll
                for (int r = 0; r < 4; ++r)
                    S[t][kt4][r] = mk[kt4][r] ? S[t][kt4][r] : -1e30f;

        // ---- row max per t: in-lane then across g ----
        float rm[2];
        #pragma unroll
        for (int t = 0; t < 2; ++t) {
            float m0 = fmaxf(fmaxf(S[t][0][0], S[t][0][1]), fmaxf(S[t][0][2], S[t][0][3]));
            float m1 = fmaxf(fmaxf(S[t][1][0], S[t][1][1]), fmaxf(S[t][1][2], S[t][1][3]));
            float m2 = fmaxf(fmaxf(S[t][2][0], S[t][2][1]), fmaxf(S[t][2][2], S[t][2][3]));
            float m3 = fmaxf(fmaxf(S[t][3][0], S[t][3][1]), fmaxf(S[t][3][2], S[t][3][3]));
            float m  = fmaxf(fmaxf(m0, m1), fmaxf(m2, m3));
            m = fmaxf(m, __shfl_xor(m, 16));
            m = fmaxf(m, __shfl_xor(m, 32));
            rm[t] = m;
        }

        // ---- defer-max rescale ----
        bool grow = (rm[0] > mrow[0] + THR) || (rm[1] > mrow[1] + THR);
        if (__any((int)grow)) {
            float mn0 = fmaxf(mrow[0], rm[0]);
            float mn1 = fmaxf(mrow[1], rm[1]);
            float rs0 = exp2f(mrow[0] - mn0);
            float rs1 = exp2f(mrow[1] - mn1);
            mrow[0] = mn0; mrow[1] = mn1;
            #pragma unroll
            for (int r = 0; r < 4; ++r) {
                float f0 = __shfl(rs0, g * 4 + r);   // S-layout -> O-layout
                float f1 = __shfl(rs1, g * 4 + r);
                #pragma unroll
                for (int dt = 0; dt < 4; ++dt) { O[0][dt][r] *= f0; O[1][dt][r] *= f1; }
                Osum[0][r] *= f0; Osum[1][r] *= f1;
            }
        }

        // ---- P = exp2(S - m), pack pairs, b64 write to per-wave LDS ----
        #pragma unroll
        for (int t = 0; t < 2; ++t) {
            int prow = t * 16 + l16;
            #pragma unroll
            for (int kt4 = 0; kt4 < 4; ++kt4) {
                float p0 = exp2f(S[t][kt4][0] - mrow[t]);
                float p1 = exp2f(S[t][kt4][1] - mrow[t]);
                float p2 = exp2f(S[t][kt4][2] - mrow[t]);
                float p3 = exp2f(S[t][kt4][3] - mrow[t]);
                unsigned int u01, u23;
                asm("v_cvt_pk_bf16_f32 %0, %1, %2" : "=v"(u01) : "v"(p0), "v"(p1));
                asm("v_cvt_pk_bf16_f32 %0, %1, %2" : "=v"(u23) : "v"(p2), "v"(p3));
                int pbyte = (kt4 * 32 + g * 8) ^ sw;
                *(uint2*)(pbb + prow * 128 + pbyte) = make_uint2(u01, u23);
            }
        }

        // ---- PV (+ ones column for row sums); vf shared across t ----
        #pragma unroll
        for (int ks = 0; ks < 2; ++ks) {
            short8 pf[2];
            #pragma unroll
            for (int t = 0; t < 2; ++t)
                pf[t] = *(const short8*)(pbb + (t * 16 + l16) * 128 + ((ks * 64 + g * 16) ^ sw));
            Osum[0] = __builtin_amdgcn_mfma_f32_16x16x32_bf16(pf[0], ones, Osum[0], 0, 0, 0);
            Osum[1] = __builtin_amdgcn_mfma_f32_16x16x32_bf16(pf[1], ones, Osum[1], 0, 0, 0);
            #pragma unroll
            for (int dt = 0; dt < 4; ++dt) {
                short8 vf = *(const short8*)((const char*)vtb
                              + ((dt * 16 + l16) * 72 + ks * 32 + g * 8) * 2);
                O[0][dt] = __builtin_amdgcn_mfma_f32_16x16x32_bf16(pf[0], vf, O[0][dt], 0, 0, 0);
                O[1][dt] = __builtin_amdgcn_mfma_f32_16x16x32_bf16(pf[1], vf, O[1][dt], 0, 0, 0);
            }
        }

        // ---- write prefetched V(kt+1) into the other buffer ----
        if (pre) {
            #pragma unroll
            for (int jj = 0; jj < 8; ++jj) {
                Vt[cur ^ 1][(dbase + jj) * 72 + kv]     = vr0[jj];
                Vt[cur ^ 1][(dbase + 8 + jj) * 72 + kv] = vr1[jj];
            }
        }
        __syncthreads();   // drains K DMA (vmcnt) + LDS writes for next iter
    }

    // ---- epilogue: normalize by Osum (already in O layout), store bf16 ----
    #pragma unroll
    for (int t = 0; t < 2; ++t)
        #pragma unroll
        for (int r = 0; r < 4; ++r) {
            float inv = 1.0f / Osum[t][r];
            int row = qrowbase + t * 16 + g * 4 + r;
            #pragma unroll
            for (int dt = 0; dt < 4; ++dt)
                ao[(size_t)row * 1024 + h * 64 + dt * 16 + l16] = f2bf(O[t][dt][r] * inv);
        }
}

extern "C" void kernel_launch(void* const* d_in, const int* in_sizes, int n_in,
                              void* d_out, int out_size, void* d_ws, size_t ws_size,
                              hipStream_t stream)
{
    const float* x  = (const float*)d_in[0];
    const int*   am = (const int*)d_in[1];
    const float* Wq = (const float*)d_in[2];
    const float* bq = (const float*)d_in[3];
    const float* Wk = (const float*)d_in[4];
    const float* bk = (const float*)d_in[5];
    const float* Wv = (const float*)d_in[6];
    const float* bv = (const float*)d_in[7];
    const float* Wo = (const float*)d_in[8];
    const float* bo = (const float*)d_in[9];
    float* out = (float*)d_out;

    const size_t NE = (size_t)Mm * Hh;           // 4M elems
    unsigned short* q    = (unsigned short*)d_ws;
    unsigned short* k    = q + NE;
    unsigned short* v    = k + NE;
    unsigned short* ao   = v + NE;
    unsigned short* xb   = ao + NE;
    unsigned short* wall = xb + NE;              // [Wq;Wk;Wv;Wo] rows
    unsigned short* wo   = wall + 3u * 1048576u;

    convert_k<<<(2 * NE) / (256 * 8), 256, 0, stream>>>(x, Wq, Wk, Wv, Wo, xb, wall);
    gemm_qkv_k<<<dim3(Mm / 128, 3072 / 128), 256, 0, stream>>>(
        xb, wall, bq, bk, bv, q, k, v);
    rope_k<<<(Mm * 128) / 256, 256, 0, stream>>>(q, k);
    flash_k<<<dim3(Ss / 128 * NHh * Bb), 256, 0, stream>>>(q, k, v, am, ao);
    gemm_out_k<<<dim3(Mm / 128, Hh / 128), 256, 0, stream>>>(ao, wo, bo, out);
}